// Round 3
// baseline (836.798 us; speedup 1.0000x reference)
//
#include <hip/hip_runtime.h>
#include <hip/hip_bf16.h>

typedef __bf16 bf16_t;
typedef __bf16 bf16x8 __attribute__((ext_vector_type(8)));
typedef __bf16 bf16x4 __attribute__((ext_vector_type(4)));
typedef float  f32x4  __attribute__((ext_vector_type(4)));

static constexpr int N_NODES = 100000;
static constexpr int N_EDGES = 300000;
static constexpr int N_GRAPH = 4096;
static constexpr int H  = 256;
static constexpr int ND = 64;
static constexpr int ZIC = 128;
static constexpr int NE = 8;
static constexpr int SCAN_B = 1024;

__device__ __forceinline__ int clampi(int v, int lo, int hi) {
  return v < lo ? lo : (v > hi ? hi : v);
}

// async 16B global -> LDS (wave-uniform LDS base + lane*16)
__device__ __forceinline__ void dma16(const bf16_t* g, bf16_t* lds_base) {
  __builtin_amdgcn_global_load_lds(
      (const __attribute__((address_space(1))) void*)g,
      (__attribute__((address_space(3))) void*)lds_base, 16, 0, 0);
}

// ------- graph segment starts (batch sorted) + zero counts/cursor --------
__global__ void compute_starts_kernel(const int* __restrict__ batch,
                                      int* __restrict__ starts,
                                      int* __restrict__ counts,
                                      int* __restrict__ cursor, int N, int G) {
  int i = blockIdx.x * blockDim.x + threadIdx.x;
  if (i >= N) return;
  counts[i] = 0;
  cursor[i] = 0;
  int b = clampi(batch[i], 0, G - 1);
  if (i == 0) {
    for (int g = 0; g <= b; ++g) starts[g] = 0;
  } else {
    int p = clampi(batch[i - 1], 0, G - 1);
    for (int g = p + 1; g <= b; ++g) starts[g] = i;
  }
  if (i == N - 1) {
    for (int g = b + 1; g <= G; ++g) starts[g] = N;
  }
}

// ---------------- CSR build ----------------
__global__ void count_deg_kernel(const int* __restrict__ dst, int* __restrict__ counts, int E, int N) {
  int e = blockIdx.x * blockDim.x + threadIdx.x;
  if (e < E) atomicAdd(&counts[clampi(dst[e], 0, N - 1)], 1);
}

__global__ __launch_bounds__(SCAN_B) void scan1_kernel(const int* __restrict__ counts,
                                                       int* __restrict__ offs,
                                                       int* __restrict__ bsum, int N) {
  __shared__ int tmp[SCAN_B];
  int i = blockIdx.x * SCAN_B + threadIdx.x;
  int v = (i < N) ? counts[i] : 0;
  tmp[threadIdx.x] = v;
  __syncthreads();
  for (int d = 1; d < SCAN_B; d <<= 1) {
    int t = (threadIdx.x >= d) ? tmp[threadIdx.x - d] : 0;
    __syncthreads();
    tmp[threadIdx.x] += t;
    __syncthreads();
  }
  if (i < N) offs[i + 1] = tmp[threadIdx.x];
  if (threadIdx.x == SCAN_B - 1) bsum[blockIdx.x] = tmp[SCAN_B - 1];
  if (i == 0) offs[0] = 0;
}

__global__ void scan2_kernel(int* __restrict__ bsum, int nblk) {
  if (blockIdx.x == 0 && threadIdx.x == 0) {
    int run = 0;
    for (int b = 0; b < nblk; ++b) { int v = bsum[b]; bsum[b] = run; run += v; }
  }
}

__global__ __launch_bounds__(SCAN_B) void scan3_kernel(int* __restrict__ offs,
                                                       const int* __restrict__ bsum, int N) {
  int i = blockIdx.x * SCAN_B + threadIdx.x;
  if (i < N) offs[i + 1] += bsum[blockIdx.x];
}

// fused: compute position AND scatter src_sorted + eattr(bf16) in one pass
__global__ void fill_scatter_kernel(const int* __restrict__ src, const int* __restrict__ dst,
                                    const float* __restrict__ eattr,
                                    const int* __restrict__ offs, int* __restrict__ cursor,
                                    int* __restrict__ src_srt, bf16_t* __restrict__ eat16,
                                    int E, int N) {
  int e = blockIdx.x * blockDim.x + threadIdx.x;
  if (e >= E) return;
  int d = clampi(dst[e], 0, N - 1);
  int pos = offs[d] + atomicAdd(&cursor[d], 1);
  if ((unsigned)pos >= (unsigned)E) return;
  int s = src[e];
  src_srt[pos] = ((unsigned)s < (unsigned)N_NODES) ? s : 0;
  const float* ea = eattr + (size_t)e * 16;
  union { bf16_t b[16]; uint4 u[2]; } pk;
#pragma unroll
  for (int k = 0; k < 16; ++k) pk.b[k] = (bf16_t)ea[k];
  uint4* dst16 = (uint4*)(eat16 + ((size_t)pos << 4));
  dst16[0] = pk.u[0];
  dst16[1] = pk.u[1];
}

// edge_W[l] (16 x 256) -> eWt[l] (256 rows x 16 cols), bf16
__global__ void build_ewt16_kernel(const float* __restrict__ edge_W,
                                   bf16_t* __restrict__ ewt) {
  int idx = blockIdx.x * blockDim.x + threadIdx.x;
  if (idx >= 3 * 256 * 16) return;
  int l = idx / (256 * 16);
  int rem = idx - l * 256 * 16;
  int n = rem >> 4, k = rem & 15;
  ewt[idx] = (bf16_t)edge_W[(size_t)l * 16 * 256 + k * 256 + n];
}

// -------- fp32 transpose + bf16 cast: W[K x Nc] -> Wt[Nc x K] (bf16) ------
__global__ void transpose_kernel(const float* __restrict__ W,
                                 bf16_t* __restrict__ Wt, int K, int Nc,
                                 size_t srcStride, size_t dstStride) {
  __shared__ float tile[32][33];
  const float* Wz = W + (size_t)blockIdx.z * srcStride;
  bf16_t* Wtz = Wt + (size_t)blockIdx.z * dstStride;
  int n0 = blockIdx.x * 32, k0 = blockIdx.y * 32;
  int tx = threadIdx.x, ty = threadIdx.y;
  for (int i = ty; i < 32; i += 8)
    tile[i][tx] = Wz[(size_t)(k0 + i) * Nc + n0 + tx];
  __syncthreads();
  for (int i = ty; i < 32; i += 8)
    Wtz[(size_t)(n0 + i) * K + k0 + tx] = (bf16_t)tile[tx][i];
}

// ---- staging loaders: 8 contiguous elements -> 8 bf16 (16B) in LDS ----
__device__ __forceinline__ void load8_to_lds(const bf16_t* p, bool valid, uint4* dst) {
  uint4 v = make_uint4(0u, 0u, 0u, 0u);
  if (valid) v = *(const uint4*)p;
  *dst = v;
}
__device__ __forceinline__ void load8_to_lds(const float* p, bool valid, uint4* dst) {
  float4 f0 = make_float4(0.f, 0.f, 0.f, 0.f), f1 = f0;
  if (valid) { f0 = *(const float4*)p; f1 = *(const float4*)(p + 4); }
  union { bf16_t b[8]; uint4 u; } pk;
  pk.b[0] = (bf16_t)f0.x; pk.b[1] = (bf16_t)f0.y;
  pk.b[2] = (bf16_t)f0.z; pk.b[3] = (bf16_t)f0.w;
  pk.b[4] = (bf16_t)f1.x; pk.b[5] = (bf16_t)f1.y;
  pk.b[6] = (bf16_t)f1.z; pk.b[7] = (bf16_t)f1.w;
  *dst = pk.u;
}

// ---------------- MFMA GEMM 128x128 (VGPR staging; fp32 or bf16 in) ------
template<int K, bool RELU, bool OUTF32, typename TIN>
__global__ __launch_bounds__(256) void gemm128_kernel(
    const TIN* __restrict__ U, const bf16_t* __restrict__ Wt,
    const float* __restrict__ bias, void* __restrict__ Out, int M, int Nc) {
  constexpr int LDT = 72;
  __shared__ bf16_t Ut[128 * LDT];
  __shared__ bf16_t Wl[128 * LDT];
  const int m0 = blockIdx.x * 128;
  const int n0 = blockIdx.y * 128;
  const int t = threadIdx.x;
  const int lane = t & 63;
  const int wave = t >> 6;
  const int wm = (wave >> 1) * 64;
  const int wn = (wave & 1) * 64;
  const int srow = t >> 1;
  const int sk = (t & 1) * 32;
  const int lr = lane & 15;
  const int lq = lane >> 4;
  const bool aok = (m0 + srow) < M;
  f32x4 acc[4][4] = {};

  for (int k0 = 0; k0 < K; k0 += 64) {
    const TIN* up = U + (size_t)(m0 + srow) * K + k0 + sk;
    const bf16_t* wp = Wt + (size_t)(n0 + srow) * K + k0 + sk;
#pragma unroll
    for (int q = 0; q < 4; ++q) {
      load8_to_lds(up + q * 8, aok, (uint4*)&Ut[srow * LDT + sk + q * 8]);
      load8_to_lds(wp + q * 8, true, (uint4*)&Wl[srow * LDT + sk + q * 8]);
    }
    __syncthreads();
#pragma unroll
    for (int s = 0; s < 2; ++s) {
      bf16x8 a[4], b[4];
#pragma unroll
      for (int mt = 0; mt < 4; ++mt)
        a[mt] = *(const bf16x8*)(&Ut[(wm + mt * 16 + lr) * LDT + s * 32 + lq * 8]);
#pragma unroll
      for (int nt = 0; nt < 4; ++nt)
        b[nt] = *(const bf16x8*)(&Wl[(wn + nt * 16 + lr) * LDT + s * 32 + lq * 8]);
#pragma unroll
      for (int mt = 0; mt < 4; ++mt)
#pragma unroll
        for (int nt = 0; nt < 4; ++nt)
          acc[mt][nt] = __builtin_amdgcn_mfma_f32_16x16x32_bf16(
              a[mt], b[nt], acc[mt][nt], 0, 0, 0);
    }
    __syncthreads();
  }

#pragma unroll
  for (int mt = 0; mt < 4; ++mt)
#pragma unroll
    for (int nt = 0; nt < 4; ++nt) {
      int col = n0 + wn + nt * 16 + lr;
      float bcol = bias[col];
#pragma unroll
      for (int r = 0; r < 4; ++r) {
        int row = m0 + wm + mt * 16 + lq * 4 + r;
        if (row < M) {
          float vv = acc[mt][nt][r] + bcol;
          if (RELU) vv = vv > 0.f ? vv : 0.f;
          if (OUTF32) ((float*)Out)[(size_t)row * Nc + col] = vv;
          else        ((bf16_t*)Out)[(size_t)row * Nc + col] = (bf16_t)vv;
        }
      }
    }
}

// ---------------- MFMA GEMM 64x64, BK=64 (heads, 2-way batched) ----------
template<int K, bool RELU, bool OUTF32, typename TIN>
__global__ __launch_bounds__(256) void gemm64x2_kernel(
    const TIN* __restrict__ U0, const bf16_t* __restrict__ Wt0,
    const float* __restrict__ b0, void* __restrict__ O0,
    const TIN* __restrict__ U1, const bf16_t* __restrict__ Wt1,
    const float* __restrict__ b1, void* __restrict__ O1, int M, int Nc) {
  constexpr int LDT = 72;
  __shared__ bf16_t Ut[64 * LDT];
  __shared__ bf16_t Wl[64 * LDT];
  const TIN*    U    = blockIdx.z ? U1 : U0;
  const bf16_t* Wt   = blockIdx.z ? Wt1 : Wt0;
  const float*  bias = blockIdx.z ? b1 : b0;
  void*         Out  = blockIdx.z ? O1 : O0;
  const int m0 = blockIdx.x * 64;
  const int n0 = blockIdx.y * 64;
  const int t = threadIdx.x;
  const int lane = t & 63;
  const int wave = t >> 6;
  const int wm = (wave >> 1) * 32;
  const int wn = (wave & 1) * 32;
  const int srow = t >> 2;
  const int sk = (t & 3) * 8;
  const int lr = lane & 15;
  const int lq = lane >> 4;
  const bool aok = (m0 + srow) < M;
  f32x4 acc[2][2] = {};

  for (int k0 = 0; k0 < K; k0 += 64) {
    const TIN* up = U + (size_t)(m0 + srow) * K + k0 + sk;
    const bf16_t* wp = Wt + (size_t)(n0 + srow) * K + k0 + sk;
    load8_to_lds(up,      aok, (uint4*)&Ut[srow * LDT + sk]);
    load8_to_lds(up + 32, aok, (uint4*)&Ut[srow * LDT + sk + 32]);
    load8_to_lds(wp,      true, (uint4*)&Wl[srow * LDT + sk]);
    load8_to_lds(wp + 32, true, (uint4*)&Wl[srow * LDT + sk + 32]);
    __syncthreads();
#pragma unroll
    for (int s = 0; s < 2; ++s) {
      bf16x8 a[2], b[2];
#pragma unroll
      for (int mt = 0; mt < 2; ++mt)
        a[mt] = *(const bf16x8*)(&Ut[(wm + mt * 16 + lr) * LDT + s * 32 + lq * 8]);
#pragma unroll
      for (int nt = 0; nt < 2; ++nt)
        b[nt] = *(const bf16x8*)(&Wl[(wn + nt * 16 + lr) * LDT + s * 32 + lq * 8]);
#pragma unroll
      for (int mt = 0; mt < 2; ++mt)
#pragma unroll
        for (int nt = 0; nt < 2; ++nt)
          acc[mt][nt] = __builtin_amdgcn_mfma_f32_16x16x32_bf16(
              a[mt], b[nt], acc[mt][nt], 0, 0, 0);
    }
    __syncthreads();
  }

#pragma unroll
  for (int mt = 0; mt < 2; ++mt)
#pragma unroll
    for (int nt = 0; nt < 2; ++nt) {
      int col = n0 + wn + nt * 16 + lr;
      float bcol = bias[col];
#pragma unroll
      for (int r = 0; r < 4; ++r) {
        int row = m0 + wm + mt * 16 + lq * 4 + r;
        if (row < M) {
          float vv = acc[mt][nt][r] + bcol;
          if (RELU) vv = vv > 0.f ? vv : 0.f;
          if (OUTF32) ((float*)Out)[(size_t)row * Nc + col] = vv;
          else        ((bf16_t*)Out)[(size_t)row * Nc + col] = (bf16_t)vv;
        }
      }
    }
}

// ------- MFMA GEMM 128x128, bf16 input, global_load_lds + XOR swizzle -----
template<int K, bool RELU, bool OUTF32>
__global__ __launch_bounds__(256) void gemm128_dma_kernel(
    const bf16_t* __restrict__ U, const bf16_t* __restrict__ Wt,
    const float* __restrict__ bias, void* __restrict__ Out, int M, int Nc) {
  __shared__ bf16_t Ut[128 * 64];
  __shared__ bf16_t Wl[128 * 64];
  const int t = threadIdx.x;
  const int lane = t & 63;
  const int wave = t >> 6;
  const int m0 = blockIdx.x * 128;
  const int n0 = blockIdx.y * 128;
  const int wm = (wave >> 1) * 64;
  const int wn = (wave & 1) * 64;
  const int lr = lane & 15;
  const int lq = lane >> 4;
  const int subrow = wave * 8 + (lane >> 3);        // + q*32
  const int lchunk = (lane & 7) ^ (lane >> 3);      // logical chunk to fetch
  f32x4 acc[4][4] = {};

  for (int k0 = 0; k0 < K; k0 += 64) {
#pragma unroll
    for (int q = 0; q < 4; ++q) {
      const int row = q * 32 + subrow;
      int urow = m0 + row; if (urow >= M) urow = M - 1;
      dma16(U + (size_t)urow * K + k0 + lchunk * 8, &Ut[(q * 32 + wave * 8) * 64]);
      dma16(Wt + (size_t)(n0 + row) * K + k0 + lchunk * 8, &Wl[(q * 32 + wave * 8) * 64]);
    }
    __syncthreads();
#pragma unroll
    for (int s = 0; s < 2; ++s) {
      bf16x8 a[4], b[4];
#pragma unroll
      for (int mt = 0; mt < 4; ++mt)
        a[mt] = *(const bf16x8*)(&Ut[(wm + mt * 16 + lr) * 64 + (((s * 4 + lq) ^ (lr & 7)) << 3)]);
#pragma unroll
      for (int nt = 0; nt < 4; ++nt)
        b[nt] = *(const bf16x8*)(&Wl[(wn + nt * 16 + lr) * 64 + (((s * 4 + lq) ^ (lr & 7)) << 3)]);
#pragma unroll
      for (int mt = 0; mt < 4; ++mt)
#pragma unroll
        for (int nt = 0; nt < 4; ++nt)
          acc[mt][nt] = __builtin_amdgcn_mfma_f32_16x16x32_bf16(
              a[mt], b[nt], acc[mt][nt], 0, 0, 0);
    }
    __syncthreads();
  }

#pragma unroll
  for (int mt = 0; mt < 4; ++mt)
#pragma unroll
    for (int nt = 0; nt < 4; ++nt) {
      int col = n0 + wn + nt * 16 + lr;
      float bcol = bias[col];
#pragma unroll
      for (int r = 0; r < 4; ++r) {
        int row = m0 + wm + mt * 16 + lq * 4 + r;
        if (row < M) {
          float vv = acc[mt][nt][r] + bcol;
          if (RELU) vv = vv > 0.f ? vv : 0.f;
          if (OUTF32) ((float*)Out)[(size_t)row * Nc + col] = vv;
          else        ((bf16_t*)Out)[(size_t)row * Nc + col] = (bf16_t)vv;
        }
      }
    }
}

// ---------------- fused GINE gather with MFMA edge-linear (v7) -----------
// v7: 16 nodes/block, 4 nodes per wave. Amortizes per-block setup (bfrag,
// eb, hs, offs) 4x, cuts block count 25000->6250 (less ramp/drain), and
// gives each wave 4 independent per-node gather chains between barriers
// for software pipelining. acc statically indexed (accv[k], k unrolled).
__global__ __launch_bounds__(256) void gine_gather_mfma_kernel(
    const bf16_t* __restrict__ h, const bf16_t* __restrict__ eat16,
    const int* __restrict__ src_sorted, const int* __restrict__ offs,
    const bf16_t* __restrict__ ewt, const float* __restrict__ eb,
    const float* __restrict__ eps_p, bf16_t* __restrict__ u) {
  constexpr int HP = H + 8;
  __shared__ bf16_t slin[2][16 * HP];  // 16.9 KB
  const int t = threadIdx.x;
  const int wave = t >> 6;
  const int lane = t & 63;
  const int lr = lane & 15;
  const int lq = lane >> 4;
  const int lane4 = lane * 4;
  const int n0 = blockIdx.x * 16;
  const int nodeB = n0 + wave * 4;

  bf16x4 hs[4];
#pragma unroll
  for (int k = 0; k < 4; ++k)
    hs[k] = *(const bf16x4*)(h + (size_t)(nodeB + k) * H + lane4);

  bf16x8 bfrag[4];
#pragma unroll
  for (int nt = 0; nt < 4; ++nt) {
    bf16x8 bv = {};
    if (lq < 2)
      bv = *(const bf16x8*)(ewt + ((wave * 64 + nt * 16 + lr) << 4) + (lq << 3));
    bfrag[nt] = bv;
  }
  float ebv[4];
#pragma unroll
  for (int i = 0; i < 4; ++i) ebv[i] = eb[lane4 + i];

  int bs = offs[n0], be = offs[n0 + 16];
  bs = clampi(bs, 0, N_EDGES);
  be = clampi(be, bs, N_EDGES);
  int nb[5];
#pragma unroll
  for (int q = 0; q < 5; ++q) nb[q] = offs[nodeB + q];
  nb[0] = clampi(nb[0], bs, be);
#pragma unroll
  for (int q = 1; q < 5; ++q) nb[q] = clampi(nb[q], nb[q - 1], be);

  f32x4 accv[4] = {};
  int parity = 0;

  for (int cb = bs; cb < be; cb += 16, parity ^= 1) {
    // --- edge-linear tile: afrag first (MFMA only waits on this load) ---
    int arow = cb + lr;
    if (arow >= N_EDGES) arow = N_EDGES - 1;
    bf16x8 afrag = {};
    if (lq < 2)
      afrag = *(const bf16x8*)(eat16 + ((size_t)arow << 4) + (lq << 3));

    // --- prefetch node-0 group-0 of this window (read-only data) -------
    int j0p = nb[0] > cb ? nb[0] : cb;
    int j1p = nb[1] < cb + 16 ? nb[1] : cb + 16;
    int sidx[4];
    bf16x4 hv[4];
    if (j0p < j1p) {
#pragma unroll
      for (int q = 0; q < 4; ++q) {
        int jj = j0p + q; if (jj > j1p - 1) jj = j1p - 1;
        sidx[q] = src_sorted[jj];
      }
    }

    f32x4 c[4];
#pragma unroll
    for (int nt = 0; nt < 4; ++nt) {
      f32x4 z = {};
      c[nt] = __builtin_amdgcn_mfma_f32_16x16x32_bf16(afrag, bfrag[nt], z, 0, 0, 0);
    }
#pragma unroll
    for (int nt = 0; nt < 4; ++nt)
#pragma unroll
      for (int r = 0; r < 4; ++r)
        slin[parity][(lq * 4 + r) * HP + wave * 64 + nt * 16 + lr] = (bf16_t)c[nt][r];

    // issue the dependent h-row gathers before the barrier
    if (j0p < j1p) {
#pragma unroll
      for (int q = 0; q < 4; ++q)
        hv[q] = *(const bf16x4*)(h + (size_t)sidx[q] * H + lane4);
    }

    __syncthreads();

    // --- consume: 4 per-node mini-loops (static acc index) -------------
#pragma unroll
    for (int k = 0; k < 4; ++k) {
      int j0 = nb[k] > cb ? nb[k] : cb;
      int j1 = nb[k + 1] < cb + 16 ? nb[k + 1] : cb + 16;
      for (int jb = j0; jb < j1; jb += 4) {
        if (k != 0 || jb != j0p) {
#pragma unroll
          for (int q = 0; q < 4; ++q) {
            int jj = jb + q; if (jj > j1 - 1) jj = j1 - 1;
            sidx[q] = src_sorted[jj];
          }
#pragma unroll
          for (int q = 0; q < 4; ++q)
            hv[q] = *(const bf16x4*)(h + (size_t)sidx[q] * H + lane4);
        }
#pragma unroll
        for (int q = 0; q < 4; ++q) {
          if (jb + q < j1) {
            bf16x4 lv = *(const bf16x4*)(&slin[parity][(jb + q - cb) * HP + lane4]);
#pragma unroll
            for (int i = 0; i < 4; ++i)
              accv[k][i] += fmaxf((float)hv[q][i] + (float)lv[i] + ebv[i], 0.f);
          }
        }
      }
    }
  }

  const float sc = 1.0f + eps_p[0];
#pragma unroll
  for (int k = 0; k < 4; ++k) {
    union { bf16x4 v; uint2 b; } o;
#pragma unroll
    for (int i = 0; i < 4; ++i) o.v[i] = (bf16_t)(sc * (float)hs[k][i] + accv[k][i]);
    *(uint2*)(u + (size_t)(nodeB + k) * H + lane4) = o.b;
  }
}

// --- GraphNorm (+relu, + optional fused mean-pool) -----------------------
// v2: 4 waves per graph (256 threads) with LDS cross-wave reduction.
__global__ __launch_bounds__(256) void graphnorm_kernel(
    const bf16_t* __restrict__ v, bf16_t* __restrict__ hout,
    const int* __restrict__ starts,
    const float* __restrict__ w, const float* __restrict__ b,
    const float* __restrict__ ms, float* __restrict__ hg) {
  constexpr int RS = 9;    // red stride (floats) - odd to spread banks
  constexpr int PS = 13;   // prm stride (floats)
  __shared__ float red[4 * 64 * RS];   // 9.2 KB
  __shared__ float prm[64 * PS];       // 3.3 KB
  const int g = blockIdx.x;
  const int t = threadIdx.x;
  const int lane = t & 63;
  const int wave = t >> 6;
  const int c0 = lane * 4;
  int s = starts[g], e = starts[g + 1];
  s = clampi(s, 0, N_NODES);
  e = clampi(e, s, N_NODES);
  const float cnt = (float)((e - s) > 1 ? (e - s) : 1);

  // pass 1: per-wave partial sums (waves stride the node range)
  float sx[4] = {0.f, 0.f, 0.f, 0.f}, sxx[4] = {0.f, 0.f, 0.f, 0.f};
  {
    int i = s + wave;
    for (; i + 4 < e; i += 8) {
      bf16x4 x0 = *(const bf16x4*)(v + (size_t)i * H + c0);
      bf16x4 x1 = *(const bf16x4*)(v + (size_t)(i + 4) * H + c0);
#pragma unroll
      for (int j = 0; j < 4; ++j) {
        float f0 = (float)x0[j], f1 = (float)x1[j];
        sx[j] += f0 + f1; sxx[j] += f0 * f0 + f1 * f1;
      }
    }
    if (i < e) {
      bf16x4 x0 = *(const bf16x4*)(v + (size_t)i * H + c0);
#pragma unroll
      for (int j = 0; j < 4; ++j) {
        float f0 = (float)x0[j];
        sx[j] += f0; sxx[j] += f0 * f0;
      }
    }
  }
  float* myred = &red[(wave * 64 + lane) * RS];
#pragma unroll
  for (int j = 0; j < 4; ++j) { myred[j] = sx[j]; myred[4 + j] = sxx[j]; }
  __syncthreads();

  // wave 0: reduce across waves, compute per-channel params
  if (wave == 0) {
#pragma unroll
    for (int j = 0; j < 4; ++j) {
      float fsx = red[lane * RS + j] + red[(64 + lane) * RS + j] +
                  red[(128 + lane) * RS + j] + red[(192 + lane) * RS + j];
      float fsxx = red[lane * RS + 4 + j] + red[(64 + lane) * RS + 4 + j] +
                   red[(128 + lane) * RS + 4 + j] + red[(192 + lane) * RS + 4 + j];
      float mean = fsx / cnt;
      float sub = ms[c0 + j] * mean;
      float var = fsxx / cnt - 2.f * sub * mean + sub * sub;
      var = fmaxf(var, 0.f);
      prm[lane * PS + j] = sub;
      prm[lane * PS + 4 + j] = rsqrtf(var + 1e-5f) * w[c0 + j];
      prm[lane * PS + 8 + j] = b[c0 + j];
    }
  }
  __syncthreads();
  float sub[4], inv[4], bb[4];
#pragma unroll
  for (int j = 0; j < 4; ++j) {
    sub[j] = prm[lane * PS + j];
    inv[j] = prm[lane * PS + 4 + j];
    bb[j] = prm[lane * PS + 8 + j];
  }

  // pass 2: normalize + relu (+ pooling partials)
  float psum[4] = {0.f, 0.f, 0.f, 0.f};
  {
    int i = s + wave;
    for (; i + 4 < e; i += 8) {
      bf16x4 x0 = *(const bf16x4*)(v + (size_t)i * H + c0);
      bf16x4 x1 = *(const bf16x4*)(v + (size_t)(i + 4) * H + c0);
      union { bf16x4 o; uint2 u; } p0, p1;
#pragma unroll
      for (int j = 0; j < 4; ++j) {
        float o0 = ((float)x0[j] - sub[j]) * inv[j] + bb[j];
        float o1 = ((float)x1[j] - sub[j]) * inv[j] + bb[j];
        o0 = o0 > 0.f ? o0 : 0.f;
        o1 = o1 > 0.f ? o1 : 0.f;
        psum[j] += o0 + o1;
        p0.o[j] = (bf16_t)o0; p1.o[j] = (bf16_t)o1;
      }
      *(uint2*)(hout + (size_t)i * H + c0) = p0.u;
      *(uint2*)(hout + (size_t)(i + 4) * H + c0) = p1.u;
    }
    if (i < e) {
      bf16x4 x0 = *(const bf16x4*)(v + (size_t)i * H + c0);
      union { bf16x4 o; uint2 u; } p0;
#pragma unroll
      for (int j = 0; j < 4; ++j) {
        float o0 = ((float)x0[j] - sub[j]) * inv[j] + bb[j];
        o0 = o0 > 0.f ? o0 : 0.f;
        psum[j] += o0;
        p0.o[j] = (bf16_t)o0;
      }
      *(uint2*)(hout + (size_t)i * H + c0) = p0.u;
    }
  }

  if (hg) {
#pragma unroll
    for (int j = 0; j < 4; ++j) myred[j] = psum[j];
    __syncthreads();
    if (wave == 0) {
#pragma unroll
      for (int j = 0; j < 4; ++j) {
        float p = red[lane * RS + j] + red[(64 + lane) * RS + j] +
                  red[(128 + lane) * RS + j] + red[(192 + lane) * RS + j];
        hg[(size_t)g * H + c0 + j] = p / cnt;
      }
    }
  }
}

// ---- fused tail heads: yhat (Nc=1) + envhat (Nc=8) in one launch --------
__global__ void head_out2_kernel(const bf16_t* __restrict__ In1, const float* __restrict__ W1,
                                 const float* __restrict__ b1, float* __restrict__ O1,
                                 const bf16_t* __restrict__ In2, const float* __restrict__ W2,
                                 const float* __restrict__ b2, float* __restrict__ O2,
                                 int M) {
  int idx = blockIdx.x * blockDim.x + threadIdx.x;
  if (idx < M) {
    float acc = b1[0];
    const bf16_t* in = In1 + (size_t)idx * ZIC;
    for (int k = 0; k < ZIC; ++k) acc += (float)in[k] * W1[k];
    O1[idx] = acc;
  } else {
    int j = idx - M;
    if (j >= M * NE) return;
    int r = j >> 3, n = j & 7;
    float acc = b2[n];
    const bf16_t* in = In2 + (size_t)r * ZIC;
    for (int k = 0; k < ZIC; ++k) acc += (float)in[k] * W2[(size_t)k * NE + n];
    O2[j] = acc;
  }
}

extern "C" void kernel_launch(void* const* d_in, const int* in_sizes, int n_in,
                              void* d_out, int out_size, void* d_ws, size_t ws_size,
                              hipStream_t stream) {
  (void)in_sizes; (void)n_in; (void)out_size; (void)ws_size;
  const float* x        = (const float*)d_in[0];
  const int*   eidx     = (const int*)d_in[1];
  const float* eattr    = (const float*)d_in[2];
  const int*   batch    = (const int*)d_in[3];
  const float* node_W   = (const float*)d_in[4];
  const float* node_b   = (const float*)d_in[5];
  const float* conv_eps = (const float*)d_in[6];
  const float* edge_W   = (const float*)d_in[7];
  const float* edge_b   = (const float*)d_in[8];
  const float* mlp_W1   = (const float*)d_in[9];
  const float* mlp_b1   = (const float*)d_in[10];
  const float* mlp_W2   = (const float*)d_in[11];
  const float* mlp_b2   = (const float*)d_in[12];
  const float* gn_w     = (const float*)d_in[13];
  const float* gn_b     = (const float*)d_in[14];
  const float* gn_ms    = (const float*)d_in[15];
  const float* finv_W1  = (const float*)d_in[16];
  const float* finv_b1  = (const float*)d_in[17];
  const float* finv_W2  = (const float*)d_in[18];
  const float* finv_b2  = (const float*)d_in[19];
  const float* fspu_W1  = (const float*)d_in[20];
  const float* fspu_b1  = (const float*)d_in[21];
  const float* fspu_W2  = (const float*)d_in[22];
  const float* fspu_b2  = (const float*)d_in[23];
  const float* pred_W1  = (const float*)d_in[24];
  const float* pred_b1  = (const float*)d_in[25];
  const float* pred_W2  = (const float*)d_in[26];
  const float* pred_b2  = (const float*)d_in[27];
  const float* adv_W1   = (const float*)d_in[28];
  const float* adv_b1   = (const float*)d_in[29];
  const float* adv_W2   = (const float*)d_in[30];
  const float* adv_b2   = (const float*)d_in[31];
  float* out = (float*)d_out;

  float* out_hg = out;                                  // [G,H]
  float* out_zi = out + (size_t)N_GRAPH * H;            // [G,ZI]
  float* out_zs = out_zi + (size_t)N_GRAPH * ZIC;       // [G,ZS]
  float* out_yh = out_zs + (size_t)N_GRAPH * ZIC;       // [G]
  float* out_ev = out_yh + N_GRAPH;                     // [G,NE]

  // workspace carve-up (~118 MiB total)
  char* wp = (char*)d_ws;
  auto alloc = [&](size_t bytes) { char* p = wp; wp += (bytes + 255) & ~(size_t)255; return p; };
  bf16_t* A        = (bf16_t*)alloc((size_t)N_NODES * H * 2);   // h / t
  bf16_t* B        = (bf16_t*)alloc((size_t)N_NODES * H * 2);   // u / v
  bf16_t* Wt       = (bf16_t*)alloc((size_t)(H * ND + 6 * H * H) * 2);
  bf16_t* WtH      = (bf16_t*)alloc((size_t)(2 * ZIC * H + 4 * ZIC * ZIC) * 2);
  bf16_t* ewt16    = (bf16_t*)alloc((size_t)3 * 256 * 16 * 2);
  bf16_t* eat16    = (bf16_t*)alloc((size_t)N_EDGES * 16 * 2);
  int*    starts   = (int*)alloc((size_t)(N_GRAPH + 1) * 4);
  int*    counts   = (int*)alloc((size_t)N_NODES * 4);
  int*    cursor   = (int*)alloc((size_t)N_NODES * 4);
  int*    offs     = (int*)alloc((size_t)(N_NODES + 1) * 4);
  int*    bsum     = (int*)alloc((size_t)SCAN_B * 4);
  int*    src_srt  = (int*)alloc((size_t)N_EDGES * 4);
  bf16_t* tmp1     = (bf16_t*)alloc((size_t)N_GRAPH * ZIC * 2);
  bf16_t* tmp2     = (bf16_t*)alloc((size_t)N_GRAPH * ZIC * 2);

  const int* srcp = eidx;
  const int* dstp = eidx + N_EDGES;
  const int nscan = (N_NODES + SCAN_B - 1) / SCAN_B;

  compute_starts_kernel<<<(N_NODES + 255) / 256, 256, 0, stream>>>(
      batch, starts, counts, cursor, N_NODES, N_GRAPH);
  count_deg_kernel<<<(N_EDGES + 255) / 256, 256, 0, stream>>>(dstp, counts, N_EDGES, N_NODES);
  scan1_kernel<<<nscan, SCAN_B, 0, stream>>>(counts, offs, bsum, N_NODES);
  scan2_kernel<<<1, 64, 0, stream>>>(bsum, nscan);
  scan3_kernel<<<nscan, SCAN_B, 0, stream>>>(offs, bsum, N_NODES);
  fill_scatter_kernel<<<(N_EDGES + 255) / 256, 256, 0, stream>>>(
      srcp, dstp, eattr, offs, cursor, src_srt, eat16, N_EDGES, N_NODES);
  build_ewt16_kernel<<<(3 * 256 * 16 + 255) / 256, 256, 0, stream>>>(edge_W, ewt16);

  bf16_t* WtN = Wt;
  bf16_t* Wt1base = Wt + H * ND;                      // l-th at stride 2*H*H
  bf16_t* Wt2base = Wt + H * ND + (size_t)H * H;      // l-th at stride 2*H*H
  auto Wt1l = [&](int l) { return Wt1base + (size_t)(2 * l) * H * H; };
  auto Wt2l = [&](int l) { return Wt2base + (size_t)(2 * l) * H * H; };
  transpose_kernel<<<dim3(H / 32, ND / 32, 1), dim3(32, 8), 0, stream>>>(node_W, WtN, ND, H, 0, 0);
  transpose_kernel<<<dim3(H / 32, H / 32, 3), dim3(32, 8), 0, stream>>>(
      mlp_W1, Wt1base, H, H, (size_t)H * H, (size_t)2 * H * H);
  transpose_kernel<<<dim3(H / 32, H / 32, 3), dim3(32, 8), 0, stream>>>(
      mlp_W2, Wt2base, H, H, (size_t)H * H, (size_t)2 * H * H);

  bf16_t* fT1 = WtH;                          // [128 x 256]
  bf16_t* fT2 = fT1 + ZIC * H;                // [128 x 128]
  bf16_t* sT1 = fT2 + ZIC * ZIC;              // [128 x 256]
  bf16_t* sT2 = sT1 + ZIC * H;                // [128 x 128]
  bf16_t* pT1 = sT2 + ZIC * ZIC;              // [128 x 128]
  bf16_t* aT1 = pT1 + ZIC * ZIC;              // [128 x 128]
  transpose_kernel<<<dim3(ZIC / 32, H / 32, 1), dim3(32, 8), 0, stream>>>(finv_W1, fT1, H, ZIC, 0, 0);
  transpose_kernel<<<dim3(ZIC / 32, ZIC / 32, 1), dim3(32, 8), 0, stream>>>(finv_W2, fT2, ZIC, ZIC, 0, 0);
  transpose_kernel<<<dim3(ZIC / 32, H / 32, 1), dim3(32, 8), 0, stream>>>(fspu_W1, sT1, H, ZIC, 0, 0);
  transpose_kernel<<<dim3(ZIC / 32, ZIC / 32, 1), dim3(32, 8), 0, stream>>>(fspu_W2, sT2, ZIC, ZIC, 0, 0);
  transpose_kernel<<<dim3(ZIC / 32, ZIC / 32, 1), dim3(32, 8), 0, stream>>>(pred_W1, pT1, ZIC, ZIC, 0, 0);
  transpose_kernel<<<dim3(ZIC / 32, ZIC / 32, 1), dim3(32, 8), 0, stream>>>(adv_W1, aT1, ZIC, ZIC, 0, 0);

  dim3 ggrid((N_NODES + 127) / 128, H / 128);
  // h = x @ node_W + node_b (fp32 input -> VGPR-staging kernel)
  gemm128_kernel<ND, false, false><<<ggrid, 256, 0, stream>>>(x, WtN, node_b, A, N_NODES, H);

  for (int l = 0; l < 3; ++l) {
    gine_gather_mfma_kernel<<<N_NODES / 16, 256, 0, stream>>>(
        A, eat16, src_srt, offs, ewt16 + (size_t)l * 256 * 16,
        edge_b + l * H, conv_eps + l, B);
    gemm128_dma_kernel<H, true,  false><<<ggrid, 256, 0, stream>>>(B, Wt1l(l), mlp_b1 + l * H, A, N_NODES, H);
    gemm128_dma_kernel<H, false, false><<<ggrid, 256, 0, stream>>>(A, Wt2l(l), mlp_b2 + l * H, B, N_NODES, H);
    graphnorm_kernel<<<N_GRAPH, 256, 0, stream>>>(B, A, starts, gn_w + l * H, gn_b + l * H,
                                                  gn_ms + l * H, (l == 2) ? out_hg : nullptr);
  }

  // heads via 64x64-tile GEMM, 2-way batched (fewer launches)
  dim3 hgrid2(N_GRAPH / 64, ZIC / 64, 2);
  gemm64x2_kernel<H, true, false, float><<<hgrid2, 256, 0, stream>>>(
      out_hg, fT1, finv_b1, tmp1, out_hg, sT1, fspu_b1, tmp2, N_GRAPH, ZIC);
  gemm64x2_kernel<ZIC, false, true, bf16_t><<<hgrid2, 256, 0, stream>>>(
      tmp1, fT2, finv_b2, out_zi, tmp2, sT2, fspu_b2, out_zs, N_GRAPH, ZIC);
  gemm64x2_kernel<ZIC, true, false, float><<<hgrid2, 256, 0, stream>>>(
      out_zi, pT1, pred_b1, tmp1, out_zi, aT1, adv_b1, tmp2, N_GRAPH, ZIC);
  head_out2_kernel<<<(N_GRAPH * (1 + NE) + 255) / 256, 256, 0, stream>>>(
      tmp1, pred_W2, pred_b2, out_yh, tmp2, adv_W2, adv_b2, out_ev, N_GRAPH);
}

// Round 4
// 817.706 us; speedup vs baseline: 1.0233x; 1.0233x over previous
//
#include <hip/hip_runtime.h>
#include <hip/hip_bf16.h>

typedef __bf16 bf16_t;
typedef __bf16 bf16x8 __attribute__((ext_vector_type(8)));
typedef __bf16 bf16x4 __attribute__((ext_vector_type(4)));
typedef float  f32x4  __attribute__((ext_vector_type(4)));

static constexpr int N_NODES = 100000;
static constexpr int N_EDGES = 300000;
static constexpr int N_GRAPH = 4096;
static constexpr int H  = 256;
static constexpr int ND = 64;
static constexpr int ZIC = 128;
static constexpr int NE = 8;
static constexpr int SCAN_B = 1024;

__device__ __forceinline__ int clampi(int v, int lo, int hi) {
  return v < lo ? lo : (v > hi ? hi : v);
}

// async 16B global -> LDS (wave-uniform LDS base + lane*16)
__device__ __forceinline__ void dma16(const bf16_t* g, bf16_t* lds_base) {
  __builtin_amdgcn_global_load_lds(
      (const __attribute__((address_space(1))) void*)g,
      (__attribute__((address_space(3))) void*)lds_base, 16, 0, 0);
}

// ------- graph segment starts (batch sorted) + zero counts/cursor --------
__global__ void compute_starts_kernel(const int* __restrict__ batch,
                                      int* __restrict__ starts,
                                      int* __restrict__ counts,
                                      int* __restrict__ cursor, int N, int G) {
  int i = blockIdx.x * blockDim.x + threadIdx.x;
  if (i >= N) return;
  counts[i] = 0;
  cursor[i] = 0;
  int b = clampi(batch[i], 0, G - 1);
  if (i == 0) {
    for (int g = 0; g <= b; ++g) starts[g] = 0;
  } else {
    int p = clampi(batch[i - 1], 0, G - 1);
    for (int g = p + 1; g <= b; ++g) starts[g] = i;
  }
  if (i == N - 1) {
    for (int g = b + 1; g <= G; ++g) starts[g] = N;
  }
}

// ---------------- CSR build ----------------
__global__ void count_deg_kernel(const int* __restrict__ dst, int* __restrict__ counts, int E, int N) {
  int e = blockIdx.x * blockDim.x + threadIdx.x;
  if (e < E) atomicAdd(&counts[clampi(dst[e], 0, N - 1)], 1);
}

__global__ __launch_bounds__(SCAN_B) void scan1_kernel(const int* __restrict__ counts,
                                                       int* __restrict__ offs,
                                                       int* __restrict__ bsum, int N) {
  __shared__ int tmp[SCAN_B];
  int i = blockIdx.x * SCAN_B + threadIdx.x;
  int v = (i < N) ? counts[i] : 0;
  tmp[threadIdx.x] = v;
  __syncthreads();
  for (int d = 1; d < SCAN_B; d <<= 1) {
    int t = (threadIdx.x >= d) ? tmp[threadIdx.x - d] : 0;
    __syncthreads();
    tmp[threadIdx.x] += t;
    __syncthreads();
  }
  if (i < N) offs[i + 1] = tmp[threadIdx.x];
  if (threadIdx.x == SCAN_B - 1) bsum[blockIdx.x] = tmp[SCAN_B - 1];
  if (i == 0) offs[0] = 0;
}

__global__ void scan2_kernel(int* __restrict__ bsum, int nblk) {
  if (blockIdx.x == 0 && threadIdx.x == 0) {
    int run = 0;
    for (int b = 0; b < nblk; ++b) { int v = bsum[b]; bsum[b] = run; run += v; }
  }
}

__global__ __launch_bounds__(SCAN_B) void scan3_kernel(int* __restrict__ offs,
                                                       const int* __restrict__ bsum, int N) {
  int i = blockIdx.x * SCAN_B + threadIdx.x;
  if (i < N) offs[i + 1] += bsum[blockIdx.x];
}

// fused: compute position AND scatter src_sorted + eattr(bf16) in one pass
__global__ void fill_scatter_kernel(const int* __restrict__ src, const int* __restrict__ dst,
                                    const float* __restrict__ eattr,
                                    const int* __restrict__ offs, int* __restrict__ cursor,
                                    int* __restrict__ src_srt, bf16_t* __restrict__ eat16,
                                    int E, int N) {
  int e = blockIdx.x * blockDim.x + threadIdx.x;
  if (e >= E) return;
  int d = clampi(dst[e], 0, N - 1);
  int pos = offs[d] + atomicAdd(&cursor[d], 1);
  if ((unsigned)pos >= (unsigned)E) return;
  int s = src[e];
  src_srt[pos] = ((unsigned)s < (unsigned)N_NODES) ? s : 0;
  const float* ea = eattr + (size_t)e * 16;
  union { bf16_t b[16]; uint4 u[2]; } pk;
#pragma unroll
  for (int k = 0; k < 16; ++k) pk.b[k] = (bf16_t)ea[k];
  uint4* dst16 = (uint4*)(eat16 + ((size_t)pos << 4));
  dst16[0] = pk.u[0];
  dst16[1] = pk.u[1];
}

// edge_W[l] (16 x 256) -> ewt[l]: stored row s holds channel (s&15)*16+(s>>4)
// (16x16 transposed row order so gine v8's per-lane MFMA outputs land on
//  16 consecutive channels -> vectorized slin writes)
__global__ void build_ewt16_kernel(const float* __restrict__ edge_W,
                                   bf16_t* __restrict__ ewt) {
  int idx = blockIdx.x * blockDim.x + threadIdx.x;
  if (idx >= 3 * 256 * 16) return;
  int l = idx / (256 * 16);
  int rem = idx - l * 256 * 16;
  int s = rem >> 4, k = rem & 15;
  int ch = ((s & 15) << 4) | (s >> 4);
  ewt[idx] = (bf16_t)edge_W[(size_t)l * 16 * 256 + k * 256 + ch];
}

// -------- fp32 transpose + bf16 cast: W[K x Nc] -> Wt[Nc x K] (bf16) ------
__global__ void transpose_kernel(const float* __restrict__ W,
                                 bf16_t* __restrict__ Wt, int K, int Nc,
                                 size_t srcStride, size_t dstStride) {
  __shared__ float tile[32][33];
  const float* Wz = W + (size_t)blockIdx.z * srcStride;
  bf16_t* Wtz = Wt + (size_t)blockIdx.z * dstStride;
  int n0 = blockIdx.x * 32, k0 = blockIdx.y * 32;
  int tx = threadIdx.x, ty = threadIdx.y;
  for (int i = ty; i < 32; i += 8)
    tile[i][tx] = Wz[(size_t)(k0 + i) * Nc + n0 + tx];
  __syncthreads();
  for (int i = ty; i < 32; i += 8)
    Wtz[(size_t)(n0 + i) * K + k0 + tx] = (bf16_t)tile[tx][i];
}

// ---- staging loaders: 8 contiguous elements -> 8 bf16 (16B) in LDS ----
__device__ __forceinline__ void load8_to_lds(const bf16_t* p, bool valid, uint4* dst) {
  uint4 v = make_uint4(0u, 0u, 0u, 0u);
  if (valid) v = *(const uint4*)p;
  *dst = v;
}
__device__ __forceinline__ void load8_to_lds(const float* p, bool valid, uint4* dst) {
  float4 f0 = make_float4(0.f, 0.f, 0.f, 0.f), f1 = f0;
  if (valid) { f0 = *(const float4*)p; f1 = *(const float4*)(p + 4); }
  union { bf16_t b[8]; uint4 u; } pk;
  pk.b[0] = (bf16_t)f0.x; pk.b[1] = (bf16_t)f0.y;
  pk.b[2] = (bf16_t)f0.z; pk.b[3] = (bf16_t)f0.w;
  pk.b[4] = (bf16_t)f1.x; pk.b[5] = (bf16_t)f1.y;
  pk.b[6] = (bf16_t)f1.z; pk.b[7] = (bf16_t)f1.w;
  *dst = pk.u;
}

// ---------------- MFMA GEMM 128x128 (VGPR staging; fp32 or bf16 in) ------
template<int K, bool RELU, bool OUTF32, typename TIN>
__global__ __launch_bounds__(256) void gemm128_kernel(
    const TIN* __restrict__ U, const bf16_t* __restrict__ Wt,
    const float* __restrict__ bias, void* __restrict__ Out, int M, int Nc) {
  constexpr int LDT = 72;
  __shared__ bf16_t Ut[128 * LDT];
  __shared__ bf16_t Wl[128 * LDT];
  const int m0 = blockIdx.x * 128;
  const int n0 = blockIdx.y * 128;
  const int t = threadIdx.x;
  const int lane = t & 63;
  const int wave = t >> 6;
  const int wm = (wave >> 1) * 64;
  const int wn = (wave & 1) * 64;
  const int srow = t >> 1;
  const int sk = (t & 1) * 32;
  const int lr = lane & 15;
  const int lq = lane >> 4;
  const bool aok = (m0 + srow) < M;
  f32x4 acc[4][4] = {};

  for (int k0 = 0; k0 < K; k0 += 64) {
    const TIN* up = U + (size_t)(m0 + srow) * K + k0 + sk;
    const bf16_t* wp = Wt + (size_t)(n0 + srow) * K + k0 + sk;
#pragma unroll
    for (int q = 0; q < 4; ++q) {
      load8_to_lds(up + q * 8, aok, (uint4*)&Ut[srow * LDT + sk + q * 8]);
      load8_to_lds(wp + q * 8, true, (uint4*)&Wl[srow * LDT + sk + q * 8]);
    }
    __syncthreads();
#pragma unroll
    for (int s = 0; s < 2; ++s) {
      bf16x8 a[4], b[4];
#pragma unroll
      for (int mt = 0; mt < 4; ++mt)
        a[mt] = *(const bf16x8*)(&Ut[(wm + mt * 16 + lr) * LDT + s * 32 + lq * 8]);
#pragma unroll
      for (int nt = 0; nt < 4; ++nt)
        b[nt] = *(const bf16x8*)(&Wl[(wn + nt * 16 + lr) * LDT + s * 32 + lq * 8]);
#pragma unroll
      for (int mt = 0; mt < 4; ++mt)
#pragma unroll
        for (int nt = 0; nt < 4; ++nt)
          acc[mt][nt] = __builtin_amdgcn_mfma_f32_16x16x32_bf16(
              a[mt], b[nt], acc[mt][nt], 0, 0, 0);
    }
    __syncthreads();
  }

#pragma unroll
  for (int mt = 0; mt < 4; ++mt)
#pragma unroll
    for (int nt = 0; nt < 4; ++nt) {
      int col = n0 + wn + nt * 16 + lr;
      float bcol = bias[col];
#pragma unroll
      for (int r = 0; r < 4; ++r) {
        int row = m0 + wm + mt * 16 + lq * 4 + r;
        if (row < M) {
          float vv = acc[mt][nt][r] + bcol;
          if (RELU) vv = vv > 0.f ? vv : 0.f;
          if (OUTF32) ((float*)Out)[(size_t)row * Nc + col] = vv;
          else        ((bf16_t*)Out)[(size_t)row * Nc + col] = (bf16_t)vv;
        }
      }
    }
}

// ---------------- MFMA GEMM 64x64, BK=64 (heads, 2-way batched) ----------
template<int K, bool RELU, bool OUTF32, typename TIN>
__global__ __launch_bounds__(256) void gemm64x2_kernel(
    const TIN* __restrict__ U0, const bf16_t* __restrict__ Wt0,
    const float* __restrict__ b0, void* __restrict__ O0,
    const TIN* __restrict__ U1, const bf16_t* __restrict__ Wt1,
    const float* __restrict__ b1, void* __restrict__ O1, int M, int Nc) {
  constexpr int LDT = 72;
  __shared__ bf16_t Ut[64 * LDT];
  __shared__ bf16_t Wl[64 * LDT];
  const TIN*    U    = blockIdx.z ? U1 : U0;
  const bf16_t* Wt   = blockIdx.z ? Wt1 : Wt0;
  const float*  bias = blockIdx.z ? b1 : b0;
  void*         Out  = blockIdx.z ? O1 : O0;
  const int m0 = blockIdx.x * 64;
  const int n0 = blockIdx.y * 64;
  const int t = threadIdx.x;
  const int lane = t & 63;
  const int wave = t >> 6;
  const int wm = (wave >> 1) * 32;
  const int wn = (wave & 1) * 32;
  const int srow = t >> 2;
  const int sk = (t & 3) * 8;
  const int lr = lane & 15;
  const int lq = lane >> 4;
  const bool aok = (m0 + srow) < M;
  f32x4 acc[2][2] = {};

  for (int k0 = 0; k0 < K; k0 += 64) {
    const TIN* up = U + (size_t)(m0 + srow) * K + k0 + sk;
    const bf16_t* wp = Wt + (size_t)(n0 + srow) * K + k0 + sk;
    load8_to_lds(up,      aok, (uint4*)&Ut[srow * LDT + sk]);
    load8_to_lds(up + 32, aok, (uint4*)&Ut[srow * LDT + sk + 32]);
    load8_to_lds(wp,      true, (uint4*)&Wl[srow * LDT + sk]);
    load8_to_lds(wp + 32, true, (uint4*)&Wl[srow * LDT + sk + 32]);
    __syncthreads();
#pragma unroll
    for (int s = 0; s < 2; ++s) {
      bf16x8 a[2], b[2];
#pragma unroll
      for (int mt = 0; mt < 2; ++mt)
        a[mt] = *(const bf16x8*)(&Ut[(wm + mt * 16 + lr) * LDT + s * 32 + lq * 8]);
#pragma unroll
      for (int nt = 0; nt < 2; ++nt)
        b[nt] = *(const bf16x8*)(&Wl[(wn + nt * 16 + lr) * LDT + s * 32 + lq * 8]);
#pragma unroll
      for (int mt = 0; mt < 2; ++mt)
#pragma unroll
        for (int nt = 0; nt < 2; ++nt)
          acc[mt][nt] = __builtin_amdgcn_mfma_f32_16x16x32_bf16(
              a[mt], b[nt], acc[mt][nt], 0, 0, 0);
    }
    __syncthreads();
  }

#pragma unroll
  for (int mt = 0; mt < 2; ++mt)
#pragma unroll
    for (int nt = 0; nt < 2; ++nt) {
      int col = n0 + wn + nt * 16 + lr;
      float bcol = bias[col];
#pragma unroll
      for (int r = 0; r < 4; ++r) {
        int row = m0 + wm + mt * 16 + lq * 4 + r;
        if (row < M) {
          float vv = acc[mt][nt][r] + bcol;
          if (RELU) vv = vv > 0.f ? vv : 0.f;
          if (OUTF32) ((float*)Out)[(size_t)row * Nc + col] = vv;
          else        ((bf16_t*)Out)[(size_t)row * Nc + col] = (bf16_t)vv;
        }
      }
    }
}

// ------- MFMA GEMM 128x128, bf16 input, global_load_lds + XOR swizzle -----
template<int K, bool RELU, bool OUTF32>
__global__ __launch_bounds__(256) void gemm128_dma_kernel(
    const bf16_t* __restrict__ U, const bf16_t* __restrict__ Wt,
    const float* __restrict__ bias, void* __restrict__ Out, int M, int Nc) {
  __shared__ bf16_t Ut[128 * 64];
  __shared__ bf16_t Wl[128 * 64];
  const int t = threadIdx.x;
  const int lane = t & 63;
  const int wave = t >> 6;
  const int m0 = blockIdx.x * 128;
  const int n0 = blockIdx.y * 128;
  const int wm = (wave >> 1) * 64;
  const int wn = (wave & 1) * 64;
  const int lr = lane & 15;
  const int lq = lane >> 4;
  const int subrow = wave * 8 + (lane >> 3);        // + q*32
  const int lchunk = (lane & 7) ^ (lane >> 3);      // logical chunk to fetch
  f32x4 acc[4][4] = {};

  for (int k0 = 0; k0 < K; k0 += 64) {
#pragma unroll
    for (int q = 0; q < 4; ++q) {
      const int row = q * 32 + subrow;
      int urow = m0 + row; if (urow >= M) urow = M - 1;
      dma16(U + (size_t)urow * K + k0 + lchunk * 8, &Ut[(q * 32 + wave * 8) * 64]);
      dma16(Wt + (size_t)(n0 + row) * K + k0 + lchunk * 8, &Wl[(q * 32 + wave * 8) * 64]);
    }
    __syncthreads();
#pragma unroll
    for (int s = 0; s < 2; ++s) {
      bf16x8 a[4], b[4];
#pragma unroll
      for (int mt = 0; mt < 4; ++mt)
        a[mt] = *(const bf16x8*)(&Ut[(wm + mt * 16 + lr) * 64 + (((s * 4 + lq) ^ (lr & 7)) << 3)]);
#pragma unroll
      for (int nt = 0; nt < 4; ++nt)
        b[nt] = *(const bf16x8*)(&Wl[(wn + nt * 16 + lr) * 64 + (((s * 4 + lq) ^ (lr & 7)) << 3)]);
#pragma unroll
      for (int mt = 0; mt < 4; ++mt)
#pragma unroll
        for (int nt = 0; nt < 4; ++nt)
          acc[mt][nt] = __builtin_amdgcn_mfma_f32_16x16x32_bf16(
              a[mt], b[nt], acc[mt][nt], 0, 0, 0);
    }
    __syncthreads();
  }

#pragma unroll
  for (int mt = 0; mt < 4; ++mt)
#pragma unroll
    for (int nt = 0; nt < 4; ++nt) {
      int col = n0 + wn + nt * 16 + lr;
      float bcol = bias[col];
#pragma unroll
      for (int r = 0; r < 4; ++r) {
        int row = m0 + wm + mt * 16 + lq * 4 + r;
        if (row < M) {
          float vv = acc[mt][nt][r] + bcol;
          if (RELU) vv = vv > 0.f ? vv : 0.f;
          if (OUTF32) ((float*)Out)[(size_t)row * Nc + col] = vv;
          else        ((bf16_t*)Out)[(size_t)row * Nc + col] = (bf16_t)vv;
        }
      }
    }
}

// ---------------- fused GINE gather with MFMA edge-linear (v8) -----------
// v8: fully wave-independent. Each wave owns 4 nodes + its own 16-edge
// window(s); computes the full 16x256 edge-linear itself (16 MFMAs, same
// GPU-total as v6 since 4x fewer wave-windows), writes a wave-PRIVATE slin
// region and consumes immediately. ZERO barriers (same-wave DS ordering).
// ewt is pre-permuted (build_ewt16) so lane (lq,lr)'s outputs for tiles
// nt=g*4+j land on channels lr*16+g*4+j -> packed uint2 slin writes.
// v7 lesson: barrier-synced blocks need per-phase balance; independence
// avoids the consume-concentration serialization entirely.
__global__ __launch_bounds__(256) void gine_gather_mfma_kernel(
    const bf16_t* __restrict__ h, const bf16_t* __restrict__ eat16,
    const int* __restrict__ src_sorted, const int* __restrict__ offs,
    const bf16_t* __restrict__ ewt, const float* __restrict__ eb,
    const float* __restrict__ eps_p, bf16_t* __restrict__ u) {
  constexpr int HPS = 264;              // channel stride per row (bf16)
  __shared__ bf16_t slin[4][16 * HPS];  // 4 waves x 8.25 KB = 33 KB
  const int t = threadIdx.x;
  const int wave = t >> 6;
  const int lane = t & 63;
  const int lr = lane & 15;
  const int lq = lane >> 4;
  const int lane4 = lane * 4;
  const int nodeB = blockIdx.x * 16 + wave * 4;
  bf16_t* sl = &slin[wave][0];

  bf16x4 hs[4];
#pragma unroll
  for (int k = 0; k < 4; ++k)
    hs[k] = *(const bf16x4*)(h + (size_t)(nodeB + k) * H + lane4);

  float ebv[4];
#pragma unroll
  for (int i = 0; i < 4; ++i) ebv[i] = eb[lane4 + i];

  int nb[5];
#pragma unroll
  for (int q = 0; q < 5; ++q) nb[q] = offs[nodeB + q];
  nb[0] = clampi(nb[0], 0, N_EDGES);
#pragma unroll
  for (int q = 1; q < 5; ++q) nb[q] = clampi(nb[q], nb[q - 1], N_EDGES);

  f32x4 accv[4] = {};

  for (int cb = nb[0]; cb < nb[4]; cb += 16) {
    // --- prefetch node-0's first gather group (read-only data) ----------
    int j0p = nb[0] > cb ? nb[0] : cb;
    int j1p = nb[1] < cb + 16 ? nb[1] : cb + 16;
    int sidx[4];
    bf16x4 hv[4];
    if (j0p < j1p) {
#pragma unroll
      for (int q = 0; q < 4; ++q) {
        int jj = j0p + q; if (jj > j1p - 1) jj = j1p - 1;
        sidx[q] = src_sorted[jj];
      }
#pragma unroll
      for (int q = 0; q < 4; ++q)
        hv[q] = *(const bf16x4*)(h + (size_t)sidx[q] * H + lane4);
    }

    // --- edge-linear tile: 16 MFMAs in 4 groups, packed slin writes -----
    int arow = cb + lr;
    if (arow >= N_EDGES) arow = N_EDGES - 1;
    bf16x8 afrag = {};
    if (lq < 2)
      afrag = *(const bf16x8*)(eat16 + ((size_t)arow << 4) + (lq << 3));

#pragma unroll
    for (int g = 0; g < 4; ++g) {
      f32x4 c4[4];
#pragma unroll
      for (int j = 0; j < 4; ++j) {
        bf16x8 bv = {};
        if (lq < 2)
          bv = *(const bf16x8*)(ewt + (((g * 4 + j) * 16 + lr) << 4) + (lq << 3));
        f32x4 z = {};
        c4[j] = __builtin_amdgcn_mfma_f32_16x16x32_bf16(afrag, bv, z, 0, 0, 0);
      }
      // lane (lq,lr): rows lq*4+r, channels lr*16 + g*4 .. +3 (consecutive)
#pragma unroll
      for (int r = 0; r < 4; ++r) {
        union { bf16_t b[4]; uint2 u2; } pk;
#pragma unroll
        for (int j = 0; j < 4; ++j) pk.b[j] = (bf16_t)c4[j][r];
        *(uint2*)(sl + (lq * 4 + r) * HPS + lr * 16 + g * 4) = pk.u2;
      }
    }

    // --- consume: 4 per-node mini-loops (static acc index, no barrier) --
#pragma unroll
    for (int k = 0; k < 4; ++k) {
      int j0 = nb[k] > cb ? nb[k] : cb;
      int j1 = nb[k + 1] < cb + 16 ? nb[k + 1] : cb + 16;
      for (int jb = j0; jb < j1; jb += 4) {
        if (k != 0 || jb != j0p) {
#pragma unroll
          for (int q = 0; q < 4; ++q) {
            int jj = jb + q; if (jj > j1 - 1) jj = j1 - 1;
            sidx[q] = src_sorted[jj];
          }
#pragma unroll
          for (int q = 0; q < 4; ++q)
            hv[q] = *(const bf16x4*)(h + (size_t)sidx[q] * H + lane4);
        }
#pragma unroll
        for (int q = 0; q < 4; ++q) {
          if (jb + q < j1) {
            bf16x4 lv = *(const bf16x4*)(sl + (jb + q - cb) * HPS + lane4);
#pragma unroll
            for (int i = 0; i < 4; ++i)
              accv[k][i] += fmaxf((float)hv[q][i] + (float)lv[i] + ebv[i], 0.f);
          }
        }
      }
    }
  }

  const float sc = 1.0f + eps_p[0];
#pragma unroll
  for (int k = 0; k < 4; ++k) {
    union { bf16x4 v; uint2 b; } o;
#pragma unroll
    for (int i = 0; i < 4; ++i) o.v[i] = (bf16_t)(sc * (float)hs[k][i] + accv[k][i]);
    *(uint2*)(u + (size_t)(nodeB + k) * H + lane4) = o.b;
  }
}

// --- GraphNorm (+relu, + optional fused mean-pool) -----------------------
// v2: 4 waves per graph (256 threads) with LDS cross-wave reduction.
__global__ __launch_bounds__(256) void graphnorm_kernel(
    const bf16_t* __restrict__ v, bf16_t* __restrict__ hout,
    const int* __restrict__ starts,
    const float* __restrict__ w, const float* __restrict__ b,
    const float* __restrict__ ms, float* __restrict__ hg) {
  constexpr int RS = 9;    // red stride (floats) - odd to spread banks
  constexpr int PS = 13;   // prm stride (floats)
  __shared__ float red[4 * 64 * RS];   // 9.2 KB
  __shared__ float prm[64 * PS];       // 3.3 KB
  const int g = blockIdx.x;
  const int t = threadIdx.x;
  const int lane = t & 63;
  const int wave = t >> 6;
  const int c0 = lane * 4;
  int s = starts[g], e = starts[g + 1];
  s = clampi(s, 0, N_NODES);
  e = clampi(e, s, N_NODES);
  const float cnt = (float)((e - s) > 1 ? (e - s) : 1);

  // pass 1: per-wave partial sums (waves stride the node range)
  float sx[4] = {0.f, 0.f, 0.f, 0.f}, sxx[4] = {0.f, 0.f, 0.f, 0.f};
  {
    int i = s + wave;
    for (; i + 4 < e; i += 8) {
      bf16x4 x0 = *(const bf16x4*)(v + (size_t)i * H + c0);
      bf16x4 x1 = *(const bf16x4*)(v + (size_t)(i + 4) * H + c0);
#pragma unroll
      for (int j = 0; j < 4; ++j) {
        float f0 = (float)x0[j], f1 = (float)x1[j];
        sx[j] += f0 + f1; sxx[j] += f0 * f0 + f1 * f1;
      }
    }
    if (i < e) {
      bf16x4 x0 = *(const bf16x4*)(v + (size_t)i * H + c0);
#pragma unroll
      for (int j = 0; j < 4; ++j) {
        float f0 = (float)x0[j];
        sx[j] += f0; sxx[j] += f0 * f0;
      }
    }
  }
  float* myred = &red[(wave * 64 + lane) * RS];
#pragma unroll
  for (int j = 0; j < 4; ++j) { myred[j] = sx[j]; myred[4 + j] = sxx[j]; }
  __syncthreads();

  // wave 0: reduce across waves, compute per-channel params
  if (wave == 0) {
#pragma unroll
    for (int j = 0; j < 4; ++j) {
      float fsx = red[lane * RS + j] + red[(64 + lane) * RS + j] +
                  red[(128 + lane) * RS + j] + red[(192 + lane) * RS + j];
      float fsxx = red[lane * RS + 4 + j] + red[(64 + lane) * RS + 4 + j] +
                   red[(128 + lane) * RS + 4 + j] + red[(192 + lane) * RS + 4 + j];
      float mean = fsx / cnt;
      float sub = ms[c0 + j] * mean;
      float var = fsxx / cnt - 2.f * sub * mean + sub * sub;
      var = fmaxf(var, 0.f);
      prm[lane * PS + j] = sub;
      prm[lane * PS + 4 + j] = rsqrtf(var + 1e-5f) * w[c0 + j];
      prm[lane * PS + 8 + j] = b[c0 + j];
    }
  }
  __syncthreads();
  float sub[4], inv[4], bb[4];
#pragma unroll
  for (int j = 0; j < 4; ++j) {
    sub[j] = prm[lane * PS + j];
    inv[j] = prm[lane * PS + 4 + j];
    bb[j] = prm[lane * PS + 8 + j];
  }

  // pass 2: normalize + relu (+ pooling partials)
  float psum[4] = {0.f, 0.f, 0.f, 0.f};
  {
    int i = s + wave;
    for (; i + 4 < e; i += 8) {
      bf16x4 x0 = *(const bf16x4*)(v + (size_t)i * H + c0);
      bf16x4 x1 = *(const bf16x4*)(v + (size_t)(i + 4) * H + c0);
      union { bf16x4 o; uint2 u; } p0, p1;
#pragma unroll
      for (int j = 0; j < 4; ++j) {
        float o0 = ((float)x0[j] - sub[j]) * inv[j] + bb[j];
        float o1 = ((float)x1[j] - sub[j]) * inv[j] + bb[j];
        o0 = o0 > 0.f ? o0 : 0.f;
        o1 = o1 > 0.f ? o1 : 0.f;
        psum[j] += o0 + o1;
        p0.o[j] = (bf16_t)o0; p1.o[j] = (bf16_t)o1;
      }
      *(uint2*)(hout + (size_t)i * H + c0) = p0.u;
      *(uint2*)(hout + (size_t)(i + 4) * H + c0) = p1.u;
    }
    if (i < e) {
      bf16x4 x0 = *(const bf16x4*)(v + (size_t)i * H + c0);
      union { bf16x4 o; uint2 u; } p0;
#pragma unroll
      for (int j = 0; j < 4; ++j) {
        float o0 = ((float)x0[j] - sub[j]) * inv[j] + bb[j];
        o0 = o0 > 0.f ? o0 : 0.f;
        psum[j] += o0;
        p0.o[j] = (bf16_t)o0;
      }
      *(uint2*)(hout + (size_t)i * H + c0) = p0.u;
    }
  }

  if (hg) {
#pragma unroll
    for (int j = 0; j < 4; ++j) myred[j] = psum[j];
    __syncthreads();
    if (wave == 0) {
#pragma unroll
      for (int j = 0; j < 4; ++j) {
        float p = red[lane * RS + j] + red[(64 + lane) * RS + j] +
                  red[(128 + lane) * RS + j] + red[(192 + lane) * RS + j];
        hg[(size_t)g * H + c0 + j] = p / cnt;
      }
    }
  }
}

// ---- fused tail heads: yhat (Nc=1) + envhat (Nc=8) in one launch --------
__global__ void head_out2_kernel(const bf16_t* __restrict__ In1, const float* __restrict__ W1,
                                 const float* __restrict__ b1, float* __restrict__ O1,
                                 const bf16_t* __restrict__ In2, const float* __restrict__ W2,
                                 const float* __restrict__ b2, float* __restrict__ O2,
                                 int M) {
  int idx = blockIdx.x * blockDim.x + threadIdx.x;
  if (idx < M) {
    float acc = b1[0];
    const bf16_t* in = In1 + (size_t)idx * ZIC;
    for (int k = 0; k < ZIC; ++k) acc += (float)in[k] * W1[k];
    O1[idx] = acc;
  } else {
    int j = idx - M;
    if (j >= M * NE) return;
    int r = j >> 3, n = j & 7;
    float acc = b2[n];
    const bf16_t* in = In2 + (size_t)r * ZIC;
    for (int k = 0; k < ZIC; ++k) acc += (float)in[k] * W2[(size_t)k * NE + n];
    O2[j] = acc;
  }
}

extern "C" void kernel_launch(void* const* d_in, const int* in_sizes, int n_in,
                              void* d_out, int out_size, void* d_ws, size_t ws_size,
                              hipStream_t stream) {
  (void)in_sizes; (void)n_in; (void)out_size; (void)ws_size;
  const float* x        = (const float*)d_in[0];
  const int*   eidx     = (const int*)d_in[1];
  const float* eattr    = (const float*)d_in[2];
  const int*   batch    = (const int*)d_in[3];
  const float* node_W   = (const float*)d_in[4];
  const float* node_b   = (const float*)d_in[5];
  const float* conv_eps = (const float*)d_in[6];
  const float* edge_W   = (const float*)d_in[7];
  const float* edge_b   = (const float*)d_in[8];
  const float* mlp_W1   = (const float*)d_in[9];
  const float* mlp_b1   = (const float*)d_in[10];
  const float* mlp_W2   = (const float*)d_in[11];
  const float* mlp_b2   = (const float*)d_in[12];
  const float* gn_w     = (const float*)d_in[13];
  const float* gn_b     = (const float*)d_in[14];
  const float* gn_ms    = (const float*)d_in[15];
  const float* finv_W1  = (const float*)d_in[16];
  const float* finv_b1  = (const float*)d_in[17];
  const float* finv_W2  = (const float*)d_in[18];
  const float* finv_b2  = (const float*)d_in[19];
  const float* fspu_W1  = (const float*)d_in[20];
  const float* fspu_b1  = (const float*)d_in[21];
  const float* fspu_W2  = (const float*)d_in[22];
  const float* fspu_b2  = (const float*)d_in[23];
  const float* pred_W1  = (const float*)d_in[24];
  const float* pred_b1  = (const float*)d_in[25];
  const float* pred_W2  = (const float*)d_in[26];
  const float* pred_b2  = (const float*)d_in[27];
  const float* adv_W1   = (const float*)d_in[28];
  const float* adv_b1   = (const float*)d_in[29];
  const float* adv_W2   = (const float*)d_in[30];
  const float* adv_b2   = (const float*)d_in[31];
  float* out = (float*)d_out;

  float* out_hg = out;                                  // [G,H]
  float* out_zi = out + (size_t)N_GRAPH * H;            // [G,ZI]
  float* out_zs = out_zi + (size_t)N_GRAPH * ZIC;       // [G,ZS]
  float* out_yh = out_zs + (size_t)N_GRAPH * ZIC;       // [G]
  float* out_ev = out_yh + N_GRAPH;                     // [G,NE]

  // workspace carve-up (~118 MiB total)
  char* wp = (char*)d_ws;
  auto alloc = [&](size_t bytes) { char* p = wp; wp += (bytes + 255) & ~(size_t)255; return p; };
  bf16_t* A        = (bf16_t*)alloc((size_t)N_NODES * H * 2);   // h / t
  bf16_t* B        = (bf16_t*)alloc((size_t)N_NODES * H * 2);   // u / v
  bf16_t* Wt       = (bf16_t*)alloc((size_t)(H * ND + 6 * H * H) * 2);
  bf16_t* WtH      = (bf16_t*)alloc((size_t)(2 * ZIC * H + 4 * ZIC * ZIC) * 2);
  bf16_t* ewt16    = (bf16_t*)alloc((size_t)3 * 256 * 16 * 2);
  bf16_t* eat16    = (bf16_t*)alloc((size_t)N_EDGES * 16 * 2);
  int*    starts   = (int*)alloc((size_t)(N_GRAPH + 1) * 4);
  int*    counts   = (int*)alloc((size_t)N_NODES * 4);
  int*    cursor   = (int*)alloc((size_t)N_NODES * 4);
  int*    offs     = (int*)alloc((size_t)(N_NODES + 1) * 4);
  int*    bsum     = (int*)alloc((size_t)SCAN_B * 4);
  int*    src_srt  = (int*)alloc((size_t)N_EDGES * 4);
  bf16_t* tmp1     = (bf16_t*)alloc((size_t)N_GRAPH * ZIC * 2);
  bf16_t* tmp2     = (bf16_t*)alloc((size_t)N_GRAPH * ZIC * 2);

  const int* srcp = eidx;
  const int* dstp = eidx + N_EDGES;
  const int nscan = (N_NODES + SCAN_B - 1) / SCAN_B;

  compute_starts_kernel<<<(N_NODES + 255) / 256, 256, 0, stream>>>(
      batch, starts, counts, cursor, N_NODES, N_GRAPH);
  count_deg_kernel<<<(N_EDGES + 255) / 256, 256, 0, stream>>>(dstp, counts, N_EDGES, N_NODES);
  scan1_kernel<<<nscan, SCAN_B, 0, stream>>>(counts, offs, bsum, N_NODES);
  scan2_kernel<<<1, 64, 0, stream>>>(bsum, nscan);
  scan3_kernel<<<nscan, SCAN_B, 0, stream>>>(offs, bsum, N_NODES);
  fill_scatter_kernel<<<(N_EDGES + 255) / 256, 256, 0, stream>>>(
      srcp, dstp, eattr, offs, cursor, src_srt, eat16, N_EDGES, N_NODES);
  build_ewt16_kernel<<<(3 * 256 * 16 + 255) / 256, 256, 0, stream>>>(edge_W, ewt16);

  bf16_t* WtN = Wt;
  bf16_t* Wt1base = Wt + H * ND;                      // l-th at stride 2*H*H
  bf16_t* Wt2base = Wt + H * ND + (size_t)H * H;      // l-th at stride 2*H*H
  auto Wt1l = [&](int l) { return Wt1base + (size_t)(2 * l) * H * H; };
  auto Wt2l = [&](int l) { return Wt2base + (size_t)(2 * l) * H * H; };
  transpose_kernel<<<dim3(H / 32, ND / 32, 1), dim3(32, 8), 0, stream>>>(node_W, WtN, ND, H, 0, 0);
  transpose_kernel<<<dim3(H / 32, H / 32, 3), dim3(32, 8), 0, stream>>>(
      mlp_W1, Wt1base, H, H, (size_t)H * H, (size_t)2 * H * H);
  transpose_kernel<<<dim3(H / 32, H / 32, 3), dim3(32, 8), 0, stream>>>(
      mlp_W2, Wt2base, H, H, (size_t)H * H, (size_t)2 * H * H);

  bf16_t* fT1 = WtH;                          // [128 x 256]
  bf16_t* fT2 = fT1 + ZIC * H;                // [128 x 128]
  bf16_t* sT1 = fT2 + ZIC * ZIC;              // [128 x 256]
  bf16_t* sT2 = sT1 + ZIC * H;                // [128 x 128]
  bf16_t* pT1 = sT2 + ZIC * ZIC;              // [128 x 128]
  bf16_t* aT1 = pT1 + ZIC * ZIC;              // [128 x 128]
  transpose_kernel<<<dim3(ZIC / 32, H / 32, 1), dim3(32, 8), 0, stream>>>(finv_W1, fT1, H, ZIC, 0, 0);
  transpose_kernel<<<dim3(ZIC / 32, ZIC / 32, 1), dim3(32, 8), 0, stream>>>(finv_W2, fT2, ZIC, ZIC, 0, 0);
  transpose_kernel<<<dim3(ZIC / 32, H / 32, 1), dim3(32, 8), 0, stream>>>(fspu_W1, sT1, H, ZIC, 0, 0);
  transpose_kernel<<<dim3(ZIC / 32, ZIC / 32, 1), dim3(32, 8), 0, stream>>>(fspu_W2, sT2, ZIC, ZIC, 0, 0);
  transpose_kernel<<<dim3(ZIC / 32, ZIC / 32, 1), dim3(32, 8), 0, stream>>>(pred_W1, pT1, ZIC, ZIC, 0, 0);
  transpose_kernel<<<dim3(ZIC / 32, ZIC / 32, 1), dim3(32, 8), 0, stream>>>(adv_W1, aT1, ZIC, ZIC, 0, 0);

  dim3 ggrid((N_NODES + 127) / 128, H / 128);
  // h = x @ node_W + node_b (fp32 input -> VGPR-staging kernel)
  gemm128_kernel<ND, false, false><<<ggrid, 256, 0, stream>>>(x, WtN, node_b, A, N_NODES, H);

  for (int l = 0; l < 3; ++l) {
    gine_gather_mfma_kernel<<<N_NODES / 16, 256, 0, stream>>>(
        A, eat16, src_srt, offs, ewt16 + (size_t)l * 256 * 16,
        edge_b + l * H, conv_eps + l, B);
    gemm128_dma_kernel<H, true,  false><<<ggrid, 256, 0, stream>>>(B, Wt1l(l), mlp_b1 + l * H, A, N_NODES, H);
    gemm128_dma_kernel<H, false, false><<<ggrid, 256, 0, stream>>>(A, Wt2l(l), mlp_b2 + l * H, B, N_NODES, H);
    graphnorm_kernel<<<N_GRAPH, 256, 0, stream>>>(B, A, starts, gn_w + l * H, gn_b + l * H,
                                                  gn_ms + l * H, (l == 2) ? out_hg : nullptr);
  }

  // heads via 64x64-tile GEMM, 2-way batched (fewer launches)
  dim3 hgrid2(N_GRAPH / 64, ZIC / 64, 2);
  gemm64x2_kernel<H, true, false, float><<<hgrid2, 256, 0, stream>>>(
      out_hg, fT1, finv_b1, tmp1, out_hg, sT1, fspu_b1, tmp2, N_GRAPH, ZIC);
  gemm64x2_kernel<ZIC, false, true, bf16_t><<<hgrid2, 256, 0, stream>>>(
      tmp1, fT2, finv_b2, out_zi, tmp2, sT2, fspu_b2, out_zs, N_GRAPH, ZIC);
  gemm64x2_kernel<ZIC, true, false, float><<<hgrid2, 256, 0, stream>>>(
      out_zi, pT1, pred_b1, tmp1, out_zi, aT1, adv_b1, tmp2, N_GRAPH, ZIC);
  head_out2_kernel<<<(N_GRAPH * (1 + NE) + 255) / 256, 256, 0, stream>>>(
      tmp1, pred_W2, pred_b2, out_yh, tmp2, adv_W2, adv_b2, out_ev, N_GRAPH);
}

// Round 5
// 729.016 us; speedup vs baseline: 1.1478x; 1.1217x over previous
//
#include <hip/hip_runtime.h>
#include <hip/hip_bf16.h>

typedef __bf16 bf16_t;
typedef __bf16 bf16x8 __attribute__((ext_vector_type(8)));
typedef __bf16 bf16x4 __attribute__((ext_vector_type(4)));
typedef float  f32x4  __attribute__((ext_vector_type(4)));

static constexpr int N_NODES = 100000;
static constexpr int N_EDGES = 300000;
static constexpr int N_GRAPH = 4096;
static constexpr int H  = 256;
static constexpr int ND = 64;
static constexpr int ZIC = 128;
static constexpr int NE = 8;
static constexpr int SCAN_B = 1024;

__device__ __forceinline__ int clampi(int v, int lo, int hi) {
  return v < lo ? lo : (v > hi ? hi : v);
}

// async 16B global -> LDS (wave-uniform LDS base + lane*16)
__device__ __forceinline__ void dma16(const bf16_t* g, bf16_t* lds_base) {
  __builtin_amdgcn_global_load_lds(
      (const __attribute__((address_space(1))) void*)g,
      (__attribute__((address_space(3))) void*)lds_base, 16, 0, 0);
}

// ------- graph segment starts (batch sorted) + zero counts/cursor --------
__global__ void compute_starts_kernel(const int* __restrict__ batch,
                                      int* __restrict__ starts,
                                      int* __restrict__ counts,
                                      int* __restrict__ cursor, int N, int G) {
  int i = blockIdx.x * blockDim.x + threadIdx.x;
  if (i >= N) return;
  counts[i] = 0;
  cursor[i] = 0;
  int b = clampi(batch[i], 0, G - 1);
  if (i == 0) {
    for (int g = 0; g <= b; ++g) starts[g] = 0;
  } else {
    int p = clampi(batch[i - 1], 0, G - 1);
    for (int g = p + 1; g <= b; ++g) starts[g] = i;
  }
  if (i == N - 1) {
    for (int g = b + 1; g <= G; ++g) starts[g] = N;
  }
}

// ---------------- CSR build ----------------
__global__ void count_deg_kernel(const int* __restrict__ dst, int* __restrict__ counts, int E, int N) {
  int e = blockIdx.x * blockDim.x + threadIdx.x;
  if (e < E) atomicAdd(&counts[clampi(dst[e], 0, N - 1)], 1);
}

__global__ __launch_bounds__(SCAN_B) void scan1_kernel(const int* __restrict__ counts,
                                                       int* __restrict__ offs,
                                                       int* __restrict__ bsum, int N) {
  __shared__ int tmp[SCAN_B];
  int i = blockIdx.x * SCAN_B + threadIdx.x;
  int v = (i < N) ? counts[i] : 0;
  tmp[threadIdx.x] = v;
  __syncthreads();
  for (int d = 1; d < SCAN_B; d <<= 1) {
    int t = (threadIdx.x >= d) ? tmp[threadIdx.x - d] : 0;
    __syncthreads();
    tmp[threadIdx.x] += t;
    __syncthreads();
  }
  if (i < N) offs[i + 1] = tmp[threadIdx.x];
  if (threadIdx.x == SCAN_B - 1) bsum[blockIdx.x] = tmp[SCAN_B - 1];
  if (i == 0) offs[0] = 0;
}

__global__ void scan2_kernel(int* __restrict__ bsum, int nblk) {
  if (blockIdx.x == 0 && threadIdx.x == 0) {
    int run = 0;
    for (int b = 0; b < nblk; ++b) { int v = bsum[b]; bsum[b] = run; run += v; }
  }
}

__global__ __launch_bounds__(SCAN_B) void scan3_kernel(int* __restrict__ offs,
                                                       const int* __restrict__ bsum, int N) {
  int i = blockIdx.x * SCAN_B + threadIdx.x;
  if (i < N) offs[i + 1] += bsum[blockIdx.x];
}

// fused: compute position AND scatter src_sorted + eattr(bf16) in one pass
__global__ void fill_scatter_kernel(const int* __restrict__ src, const int* __restrict__ dst,
                                    const float* __restrict__ eattr,
                                    const int* __restrict__ offs, int* __restrict__ cursor,
                                    int* __restrict__ src_srt, bf16_t* __restrict__ eat16,
                                    int E, int N) {
  int e = blockIdx.x * blockDim.x + threadIdx.x;
  if (e >= E) return;
  int d = clampi(dst[e], 0, N - 1);
  int pos = offs[d] + atomicAdd(&cursor[d], 1);
  if ((unsigned)pos >= (unsigned)E) return;
  int s = src[e];
  src_srt[pos] = ((unsigned)s < (unsigned)N_NODES) ? s : 0;
  const float* ea = eattr + (size_t)e * 16;
  union { bf16_t b[16]; uint4 u[2]; } pk;
#pragma unroll
  for (int k = 0; k < 16; ++k) pk.b[k] = (bf16_t)ea[k];
  uint4* dst16 = (uint4*)(eat16 + ((size_t)pos << 4));
  dst16[0] = pk.u[0];
  dst16[1] = pk.u[1];
}

// edge_W[l] (16 x 256) -> eWt[l] (256 rows x 16 cols), bf16  (v6 layout)
__global__ void build_ewt16_kernel(const float* __restrict__ edge_W,
                                   bf16_t* __restrict__ ewt) {
  int idx = blockIdx.x * blockDim.x + threadIdx.x;
  if (idx >= 3 * 256 * 16) return;
  int l = idx / (256 * 16);
  int rem = idx - l * 256 * 16;
  int n = rem >> 4, k = rem & 15;
  ewt[idx] = (bf16_t)edge_W[(size_t)l * 16 * 256 + k * 256 + n];
}

// -------- fp32 transpose + bf16 cast: W[K x Nc] -> Wt[Nc x K] (bf16) ------
__global__ void transpose_kernel(const float* __restrict__ W,
                                 bf16_t* __restrict__ Wt, int K, int Nc,
                                 size_t srcStride, size_t dstStride) {
  __shared__ float tile[32][33];
  const float* Wz = W + (size_t)blockIdx.z * srcStride;
  bf16_t* Wtz = Wt + (size_t)blockIdx.z * dstStride;
  int n0 = blockIdx.x * 32, k0 = blockIdx.y * 32;
  int tx = threadIdx.x, ty = threadIdx.y;
  for (int i = ty; i < 32; i += 8)
    tile[i][tx] = Wz[(size_t)(k0 + i) * Nc + n0 + tx];
  __syncthreads();
  for (int i = ty; i < 32; i += 8)
    Wtz[(size_t)(n0 + i) * K + k0 + tx] = (bf16_t)tile[tx][i];
}

// ---- staging loaders: 8 contiguous elements -> 8 bf16 (16B) in LDS ----
__device__ __forceinline__ void load8_to_lds(const bf16_t* p, bool valid, uint4* dst) {
  uint4 v = make_uint4(0u, 0u, 0u, 0u);
  if (valid) v = *(const uint4*)p;
  *dst = v;
}
__device__ __forceinline__ void load8_to_lds(const float* p, bool valid, uint4* dst) {
  float4 f0 = make_float4(0.f, 0.f, 0.f, 0.f), f1 = f0;
  if (valid) { f0 = *(const float4*)p; f1 = *(const float4*)(p + 4); }
  union { bf16_t b[8]; uint4 u; } pk;
  pk.b[0] = (bf16_t)f0.x; pk.b[1] = (bf16_t)f0.y;
  pk.b[2] = (bf16_t)f0.z; pk.b[3] = (bf16_t)f0.w;
  pk.b[4] = (bf16_t)f1.x; pk.b[5] = (bf16_t)f1.y;
  pk.b[6] = (bf16_t)f1.z; pk.b[7] = (bf16_t)f1.w;
  *dst = pk.u;
}

// ---------------- MFMA GEMM 128x128 (VGPR staging; fp32 or bf16 in) ------
template<int K, bool RELU, bool OUTF32, typename TIN>
__global__ __launch_bounds__(256) void gemm128_kernel(
    const TIN* __restrict__ U, const bf16_t* __restrict__ Wt,
    const float* __restrict__ bias, void* __restrict__ Out, int M, int Nc) {
  constexpr int LDT = 72;
  __shared__ bf16_t Ut[128 * LDT];
  __shared__ bf16_t Wl[128 * LDT];
  const int m0 = blockIdx.x * 128;
  const int n0 = blockIdx.y * 128;
  const int t = threadIdx.x;
  const int lane = t & 63;
  const int wave = t >> 6;
  const int wm = (wave >> 1) * 64;
  const int wn = (wave & 1) * 64;
  const int srow = t >> 1;
  const int sk = (t & 1) * 32;
  const int lr = lane & 15;
  const int lq = lane >> 4;
  const bool aok = (m0 + srow) < M;
  f32x4 acc[4][4] = {};

  for (int k0 = 0; k0 < K; k0 += 64) {
    const TIN* up = U + (size_t)(m0 + srow) * K + k0 + sk;
    const bf16_t* wp = Wt + (size_t)(n0 + srow) * K + k0 + sk;
#pragma unroll
    for (int q = 0; q < 4; ++q) {
      load8_to_lds(up + q * 8, aok, (uint4*)&Ut[srow * LDT + sk + q * 8]);
      load8_to_lds(wp + q * 8, true, (uint4*)&Wl[srow * LDT + sk + q * 8]);
    }
    __syncthreads();
#pragma unroll
    for (int s = 0; s < 2; ++s) {
      bf16x8 a[4], b[4];
#pragma unroll
      for (int mt = 0; mt < 4; ++mt)
        a[mt] = *(const bf16x8*)(&Ut[(wm + mt * 16 + lr) * LDT + s * 32 + lq * 8]);
#pragma unroll
      for (int nt = 0; nt < 4; ++nt)
        b[nt] = *(const bf16x8*)(&Wl[(wn + nt * 16 + lr) * LDT + s * 32 + lq * 8]);
#pragma unroll
      for (int mt = 0; mt < 4; ++mt)
#pragma unroll
        for (int nt = 0; nt < 4; ++nt)
          acc[mt][nt] = __builtin_amdgcn_mfma_f32_16x16x32_bf16(
              a[mt], b[nt], acc[mt][nt], 0, 0, 0);
    }
    __syncthreads();
  }

#pragma unroll
  for (int mt = 0; mt < 4; ++mt)
#pragma unroll
    for (int nt = 0; nt < 4; ++nt) {
      int col = n0 + wn + nt * 16 + lr;
      float bcol = bias[col];
#pragma unroll
      for (int r = 0; r < 4; ++r) {
        int row = m0 + wm + mt * 16 + lq * 4 + r;
        if (row < M) {
          float vv = acc[mt][nt][r] + bcol;
          if (RELU) vv = vv > 0.f ? vv : 0.f;
          if (OUTF32) ((float*)Out)[(size_t)row * Nc + col] = vv;
          else        ((bf16_t*)Out)[(size_t)row * Nc + col] = (bf16_t)vv;
        }
      }
    }
}

// ---------------- MFMA GEMM 64x64, BK=64 (heads, 2-way batched) ----------
template<int K, bool RELU, bool OUTF32, typename TIN>
__global__ __launch_bounds__(256) void gemm64x2_kernel(
    const TIN* __restrict__ U0, const bf16_t* __restrict__ Wt0,
    const float* __restrict__ b0, void* __restrict__ O0,
    const TIN* __restrict__ U1, const bf16_t* __restrict__ Wt1,
    const float* __restrict__ b1, void* __restrict__ O1, int M, int Nc) {
  constexpr int LDT = 72;
  __shared__ bf16_t Ut[64 * LDT];
  __shared__ bf16_t Wl[64 * LDT];
  const TIN*    U    = blockIdx.z ? U1 : U0;
  const bf16_t* Wt   = blockIdx.z ? Wt1 : Wt0;
  const float*  bias = blockIdx.z ? b1 : b0;
  void*         Out  = blockIdx.z ? O1 : O0;
  const int m0 = blockIdx.x * 64;
  const int n0 = blockIdx.y * 64;
  const int t = threadIdx.x;
  const int lane = t & 63;
  const int wave = t >> 6;
  const int wm = (wave >> 1) * 32;
  const int wn = (wave & 1) * 32;
  const int srow = t >> 2;
  const int sk = (t & 3) * 8;
  const int lr = lane & 15;
  const int lq = lane >> 4;
  const bool aok = (m0 + srow) < M;
  f32x4 acc[2][2] = {};

  for (int k0 = 0; k0 < K; k0 += 64) {
    const TIN* up = U + (size_t)(m0 + srow) * K + k0 + sk;
    const bf16_t* wp = Wt + (size_t)(n0 + srow) * K + k0 + sk;
    load8_to_lds(up,      aok, (uint4*)&Ut[srow * LDT + sk]);
    load8_to_lds(up + 32, aok, (uint4*)&Ut[srow * LDT + sk + 32]);
    load8_to_lds(wp,      true, (uint4*)&Wl[srow * LDT + sk]);
    load8_to_lds(wp + 32, true, (uint4*)&Wl[srow * LDT + sk + 32]);
    __syncthreads();
#pragma unroll
    for (int s = 0; s < 2; ++s) {
      bf16x8 a[2], b[2];
#pragma unroll
      for (int mt = 0; mt < 2; ++mt)
        a[mt] = *(const bf16x8*)(&Ut[(wm + mt * 16 + lr) * LDT + s * 32 + lq * 8]);
#pragma unroll
      for (int nt = 0; nt < 2; ++nt)
        b[nt] = *(const bf16x8*)(&Wl[(wn + nt * 16 + lr) * LDT + s * 32 + lq * 8]);
#pragma unroll
      for (int mt = 0; mt < 2; ++mt)
#pragma unroll
        for (int nt = 0; nt < 2; ++nt)
          acc[mt][nt] = __builtin_amdgcn_mfma_f32_16x16x32_bf16(
              a[mt], b[nt], acc[mt][nt], 0, 0, 0);
    }
    __syncthreads();
  }

#pragma unroll
  for (int mt = 0; mt < 2; ++mt)
#pragma unroll
    for (int nt = 0; nt < 2; ++nt) {
      int col = n0 + wn + nt * 16 + lr;
      float bcol = bias[col];
#pragma unroll
      for (int r = 0; r < 4; ++r) {
        int row = m0 + wm + mt * 16 + lq * 4 + r;
        if (row < M) {
          float vv = acc[mt][nt][r] + bcol;
          if (RELU) vv = vv > 0.f ? vv : 0.f;
          if (OUTF32) ((float*)Out)[(size_t)row * Nc + col] = vv;
          else        ((bf16_t*)Out)[(size_t)row * Nc + col] = (bf16_t)vv;
        }
      }
    }
}

// ------- MFMA GEMM 128x256 (full-H tile), bf16 in, dma16 + XOR swizzle ----
// 512 threads / 8 waves (2 M x 4 N). Reads A once per GEMM (vs twice for
// the 128x128 tile): ~103 MB instead of ~154 MB per MLP GEMM, half the
// blocks. Staging pattern identical to the proven gemm128_dma (subrow /
// lchunk pre-swizzled source, XOR'd read), extended to 256 W-rows.
template<int K, bool RELU>
__global__ __launch_bounds__(512) void gemm256_dma_kernel(
    const bf16_t* __restrict__ U, const bf16_t* __restrict__ Wt,
    const float* __restrict__ bias, bf16_t* __restrict__ Out, int M) {
  __shared__ bf16_t Ut[128 * 64];   // 16 KB
  __shared__ bf16_t Wl[256 * 64];   // 32 KB
  const int t = threadIdx.x;
  const int lane = t & 63;
  const int wave = t >> 6;                 // 0..7
  const int m0 = blockIdx.x * 128;
  const int wm = (wave >> 2) * 64;         // 0,64
  const int wn = (wave & 3) * 64;          // 0,64,128,192
  const int lr = lane & 15;
  const int lq = lane >> 4;
  const int subrow = lane >> 3;            // 0..7 within 8-row group
  const int lchunk = (lane & 7) ^ subrow;  // pre-swizzled col chunk
  f32x4 acc[4][4] = {};

  for (int k0 = 0; k0 < K; k0 += 64) {
    // stage Ut: 2 chunks of 64 rows (each wave covers 8 rows per call)
#pragma unroll
    for (int c = 0; c < 2; ++c) {
      int urow = m0 + c * 64 + wave * 8 + subrow;
      if (urow >= M) urow = M - 1;
      dma16(U + (size_t)urow * K + k0 + lchunk * 8, &Ut[(c * 64 + wave * 8) * 64]);
    }
    // stage Wl: 4 chunks of 64 rows (256 N-rows total)
#pragma unroll
    for (int c = 0; c < 4; ++c) {
      int wrow = c * 64 + wave * 8 + subrow;
      dma16(Wt + (size_t)wrow * K + k0 + lchunk * 8, &Wl[(c * 64 + wave * 8) * 64]);
    }
    __syncthreads();
#pragma unroll
    for (int s = 0; s < 2; ++s) {
      bf16x8 a[4], b[4];
#pragma unroll
      for (int mt = 0; mt < 4; ++mt)
        a[mt] = *(const bf16x8*)(&Ut[(wm + mt * 16 + lr) * 64 + (((s * 4 + lq) ^ (lr & 7)) << 3)]);
#pragma unroll
      for (int nt = 0; nt < 4; ++nt)
        b[nt] = *(const bf16x8*)(&Wl[(wn + nt * 16 + lr) * 64 + (((s * 4 + lq) ^ (lr & 7)) << 3)]);
#pragma unroll
      for (int mt = 0; mt < 4; ++mt)
#pragma unroll
        for (int nt = 0; nt < 4; ++nt)
          acc[mt][nt] = __builtin_amdgcn_mfma_f32_16x16x32_bf16(
              a[mt], b[nt], acc[mt][nt], 0, 0, 0);
    }
    __syncthreads();
  }

#pragma unroll
  for (int mt = 0; mt < 4; ++mt)
#pragma unroll
    for (int nt = 0; nt < 4; ++nt) {
      int col = wn + nt * 16 + lr;
      float bcol = bias[col];
#pragma unroll
      for (int r = 0; r < 4; ++r) {
        int row = m0 + wm + mt * 16 + lq * 4 + r;
        if (row < M) {
          float vv = acc[mt][nt][r] + bcol;
          if (RELU) vv = vv > 0.f ? vv : 0.f;
          Out[(size_t)row * H + col] = (bf16_t)vv;
        }
      }
    }
}

// ---------------- fused GINE gather with MFMA edge-linear (v6) -----------
// v6 = proven best (64 us): 4 nodes/block cooperative, bias as inner-loop
// ebv adds, pre-barrier prefetch of the first gather group. v7 (16-node
// barrier-coupled) and v8 (wave-independent 16-MFMA) both regressed.
__global__ __launch_bounds__(256) void gine_gather_mfma_kernel(
    const bf16_t* __restrict__ h, const bf16_t* __restrict__ eat16,
    const int* __restrict__ src_sorted, const int* __restrict__ offs,
    const bf16_t* __restrict__ ewt, const float* __restrict__ eb,
    const float* __restrict__ eps_p, bf16_t* __restrict__ u) {
  constexpr int HP = H + 8;
  __shared__ bf16_t slin[2][16 * HP];  // 16.9 KB
  const int t = threadIdx.x;
  const int wave = t >> 6;
  const int lane = t & 63;
  const int lr = lane & 15;
  const int lq = lane >> 4;
  const int lane4 = lane * 4;
  const int n0 = blockIdx.x * 4;
  const int nodeN = n0 + wave;

  bf16x4 hs = *(const bf16x4*)(h + (size_t)nodeN * H + lane4);

  bf16x8 bfrag[4];
#pragma unroll
  for (int nt = 0; nt < 4; ++nt) {
    bf16x8 bv = {};
    if (lq < 2)
      bv = *(const bf16x8*)(ewt + ((wave * 64 + nt * 16 + lr) << 4) + (lq << 3));
    bfrag[nt] = bv;
  }
  float ebv[4];
#pragma unroll
  for (int i = 0; i < 4; ++i) ebv[i] = eb[lane4 + i];

  int bs = offs[n0], be = offs[n0 + 4];
  bs = clampi(bs, 0, N_EDGES);
  be = clampi(be, bs, N_EDGES);
  int ns = offs[nodeN], ne = offs[nodeN + 1];
  ns = clampi(ns, bs, be);
  ne = clampi(ne, ns, be);

  float acc[4] = {0.f, 0.f, 0.f, 0.f};
  int parity = 0;

  for (int cb = bs; cb < be; cb += 16, parity ^= 1) {
    // --- edge-linear tile: afrag first (MFMA only waits on this load) ---
    int arow = cb + lr;
    if (arow >= N_EDGES) arow = N_EDGES - 1;
    bf16x8 afrag = {};
    if (lq < 2)
      afrag = *(const bf16x8*)(eat16 + ((size_t)arow << 4) + (lq << 3));

    // --- prefetch group 0 of this wave's own edges (read-only data) ----
    int j0 = ns > cb ? ns : cb;
    int j1 = ne < cb + 16 ? ne : cb + 16;
    int sidx[4];
    bf16x4 hv[4];
    if (j0 < j1) {
#pragma unroll
      for (int q = 0; q < 4; ++q) {
        int jj = j0 + q; if (jj > j1 - 1) jj = j1 - 1;
        sidx[q] = src_sorted[jj];
      }
    }

    f32x4 c[4];
#pragma unroll
    for (int nt = 0; nt < 4; ++nt) {
      f32x4 z = {};
      c[nt] = __builtin_amdgcn_mfma_f32_16x16x32_bf16(afrag, bfrag[nt], z, 0, 0, 0);
    }
#pragma unroll
    for (int nt = 0; nt < 4; ++nt)
#pragma unroll
      for (int r = 0; r < 4; ++r)
        slin[parity][(lq * 4 + r) * HP + wave * 64 + nt * 16 + lr] = (bf16_t)c[nt][r];

    // issue the dependent h-row gathers before the barrier
    if (j0 < j1) {
#pragma unroll
      for (int q = 0; q < 4; ++q)
        hv[q] = *(const bf16x4*)(h + (size_t)sidx[q] * H + lane4);
    }

    __syncthreads();

    for (int jb = j0; jb < j1; jb += 4) {
      if (jb != j0) {
#pragma unroll
        for (int q = 0; q < 4; ++q) {
          int jj = jb + q; if (jj > j1 - 1) jj = j1 - 1;
          sidx[q] = src_sorted[jj];
        }
#pragma unroll
        for (int q = 0; q < 4; ++q)
          hv[q] = *(const bf16x4*)(h + (size_t)sidx[q] * H + lane4);
      }
#pragma unroll
      for (int q = 0; q < 4; ++q) {
        if (jb + q < j1) {
          bf16x4 lv = *(const bf16x4*)(&slin[parity][(jb + q - cb) * HP + lane4]);
#pragma unroll
          for (int i = 0; i < 4; ++i)
            acc[i] += fmaxf((float)hv[q][i] + (float)lv[i] + ebv[i], 0.f);
        }
      }
    }
  }

  const float sc = 1.0f + eps_p[0];
  union { bf16x4 v; uint2 b; } o;
#pragma unroll
  for (int i = 0; i < 4; ++i) o.v[i] = (bf16_t)(sc * (float)hs[i] + acc[i]);
  *(uint2*)(u + (size_t)nodeN * H + lane4) = o.b;
}

// --- GraphNorm (+relu, + optional fused mean-pool) -----------------------
// v2: 4 waves per graph (256 threads) with LDS cross-wave reduction.
__global__ __launch_bounds__(256) void graphnorm_kernel(
    const bf16_t* __restrict__ v, bf16_t* __restrict__ hout,
    const int* __restrict__ starts,
    const float* __restrict__ w, const float* __restrict__ b,
    const float* __restrict__ ms, float* __restrict__ hg) {
  constexpr int RS = 9;    // red stride (floats) - odd to spread banks
  constexpr int PS = 13;   // prm stride (floats)
  __shared__ float red[4 * 64 * RS];   // 9.2 KB
  __shared__ float prm[64 * PS];       // 3.3 KB
  const int g = blockIdx.x;
  const int t = threadIdx.x;
  const int lane = t & 63;
  const int wave = t >> 6;
  const int c0 = lane * 4;
  int s = starts[g], e = starts[g + 1];
  s = clampi(s, 0, N_NODES);
  e = clampi(e, s, N_NODES);
  const float cnt = (float)((e - s) > 1 ? (e - s) : 1);

  // pass 1: per-wave partial sums (waves stride the node range)
  float sx[4] = {0.f, 0.f, 0.f, 0.f}, sxx[4] = {0.f, 0.f, 0.f, 0.f};
  {
    int i = s + wave;
    for (; i + 4 < e; i += 8) {
      bf16x4 x0 = *(const bf16x4*)(v + (size_t)i * H + c0);
      bf16x4 x1 = *(const bf16x4*)(v + (size_t)(i + 4) * H + c0);
#pragma unroll
      for (int j = 0; j < 4; ++j) {
        float f0 = (float)x0[j], f1 = (float)x1[j];
        sx[j] += f0 + f1; sxx[j] += f0 * f0 + f1 * f1;
      }
    }
    if (i < e) {
      bf16x4 x0 = *(const bf16x4*)(v + (size_t)i * H + c0);
#pragma unroll
      for (int j = 0; j < 4; ++j) {
        float f0 = (float)x0[j];
        sx[j] += f0; sxx[j] += f0 * f0;
      }
    }
  }
  float* myred = &red[(wave * 64 + lane) * RS];
#pragma unroll
  for (int j = 0; j < 4; ++j) { myred[j] = sx[j]; myred[4 + j] = sxx[j]; }
  __syncthreads();

  // wave 0: reduce across waves, compute per-channel params
  if (wave == 0) {
#pragma unroll
    for (int j = 0; j < 4; ++j) {
      float fsx = red[lane * RS + j] + red[(64 + lane) * RS + j] +
                  red[(128 + lane) * RS + j] + red[(192 + lane) * RS + j];
      float fsxx = red[lane * RS + 4 + j] + red[(64 + lane) * RS + 4 + j] +
                   red[(128 + lane) * RS + 4 + j] + red[(192 + lane) * RS + 4 + j];
      float mean = fsx / cnt;
      float sub = ms[c0 + j] * mean;
      float var = fsxx / cnt - 2.f * sub * mean + sub * sub;
      var = fmaxf(var, 0.f);
      prm[lane * PS + j] = sub;
      prm[lane * PS + 4 + j] = rsqrtf(var + 1e-5f) * w[c0 + j];
      prm[lane * PS + 8 + j] = b[c0 + j];
    }
  }
  __syncthreads();
  float sub[4], inv[4], bb[4];
#pragma unroll
  for (int j = 0; j < 4; ++j) {
    sub[j] = prm[lane * PS + j];
    inv[j] = prm[lane * PS + 4 + j];
    bb[j] = prm[lane * PS + 8 + j];
  }

  // pass 2: normalize + relu (+ pooling partials)
  float psum[4] = {0.f, 0.f, 0.f, 0.f};
  {
    int i = s + wave;
    for (; i + 4 < e; i += 8) {
      bf16x4 x0 = *(const bf16x4*)(v + (size_t)i * H + c0);
      bf16x4 x1 = *(const bf16x4*)(v + (size_t)(i + 4) * H + c0);
      union { bf16x4 o; uint2 u; } p0, p1;
#pragma unroll
      for (int j = 0; j < 4; ++j) {
        float o0 = ((float)x0[j] - sub[j]) * inv[j] + bb[j];
        float o1 = ((float)x1[j] - sub[j]) * inv[j] + bb[j];
        o0 = o0 > 0.f ? o0 : 0.f;
        o1 = o1 > 0.f ? o1 : 0.f;
        psum[j] += o0 + o1;
        p0.o[j] = (bf16_t)o0; p1.o[j] = (bf16_t)o1;
      }
      *(uint2*)(hout + (size_t)i * H + c0) = p0.u;
      *(uint2*)(hout + (size_t)(i + 4) * H + c0) = p1.u;
    }
    if (i < e) {
      bf16x4 x0 = *(const bf16x4*)(v + (size_t)i * H + c0);
      union { bf16x4 o; uint2 u; } p0;
#pragma unroll
      for (int j = 0; j < 4; ++j) {
        float o0 = ((float)x0[j] - sub[j]) * inv[j] + bb[j];
        o0 = o0 > 0.f ? o0 : 0.f;
        psum[j] += o0;
        p0.o[j] = (bf16_t)o0;
      }
      *(uint2*)(hout + (size_t)i * H + c0) = p0.u;
    }
  }

  if (hg) {
#pragma unroll
    for (int j = 0; j < 4; ++j) myred[j] = psum[j];
    __syncthreads();
    if (wave == 0) {
#pragma unroll
      for (int j = 0; j < 4; ++j) {
        float p = red[lane * RS + j] + red[(64 + lane) * RS + j] +
                  red[(128 + lane) * RS + j] + red[(192 + lane) * RS + j];
        hg[(size_t)g * H + c0 + j] = p / cnt;
      }
    }
  }
}

// ---- fused tail heads: yhat (Nc=1) + envhat (Nc=8) in one launch --------
__global__ void head_out2_kernel(const bf16_t* __restrict__ In1, const float* __restrict__ W1,
                                 const float* __restrict__ b1, float* __restrict__ O1,
                                 const bf16_t* __restrict__ In2, const float* __restrict__ W2,
                                 const float* __restrict__ b2, float* __restrict__ O2,
                                 int M) {
  int idx = blockIdx.x * blockDim.x + threadIdx.x;
  if (idx < M) {
    float acc = b1[0];
    const bf16_t* in = In1 + (size_t)idx * ZIC;
    for (int k = 0; k < ZIC; ++k) acc += (float)in[k] * W1[k];
    O1[idx] = acc;
  } else {
    int j = idx - M;
    if (j >= M * NE) return;
    int r = j >> 3, n = j & 7;
    float acc = b2[n];
    const bf16_t* in = In2 + (size_t)r * ZIC;
    for (int k = 0; k < ZIC; ++k) acc += (float)in[k] * W2[(size_t)k * NE + n];
    O2[j] = acc;
  }
}

extern "C" void kernel_launch(void* const* d_in, const int* in_sizes, int n_in,
                              void* d_out, int out_size, void* d_ws, size_t ws_size,
                              hipStream_t stream) {
  (void)in_sizes; (void)n_in; (void)out_size; (void)ws_size;
  const float* x        = (const float*)d_in[0];
  const int*   eidx     = (const int*)d_in[1];
  const float* eattr    = (const float*)d_in[2];
  const int*   batch    = (const int*)d_in[3];
  const float* node_W   = (const float*)d_in[4];
  const float* node_b   = (const float*)d_in[5];
  const float* conv_eps = (const float*)d_in[6];
  const float* edge_W   = (const float*)d_in[7];
  const float* edge_b   = (const float*)d_in[8];
  const float* mlp_W1   = (const float*)d_in[9];
  const float* mlp_b1   = (const float*)d_in[10];
  const float* mlp_W2   = (const float*)d_in[11];
  const float* mlp_b2   = (const float*)d_in[12];
  const float* gn_w     = (const float*)d_in[13];
  const float* gn_b     = (const float*)d_in[14];
  const float* gn_ms    = (const float*)d_in[15];
  const float* finv_W1  = (const float*)d_in[16];
  const float* finv_b1  = (const float*)d_in[17];
  const float* finv_W2  = (const float*)d_in[18];
  const float* finv_b2  = (const float*)d_in[19];
  const float* fspu_W1  = (const float*)d_in[20];
  const float* fspu_b1  = (const float*)d_in[21];
  const float* fspu_W2  = (const float*)d_in[22];
  const float* fspu_b2  = (const float*)d_in[23];
  const float* pred_W1  = (const float*)d_in[24];
  const float* pred_b1  = (const float*)d_in[25];
  const float* pred_W2  = (const float*)d_in[26];
  const float* pred_b2  = (const float*)d_in[27];
  const float* adv_W1   = (const float*)d_in[28];
  const float* adv_b1   = (const float*)d_in[29];
  const float* adv_W2   = (const float*)d_in[30];
  const float* adv_b2   = (const float*)d_in[31];
  float* out = (float*)d_out;

  float* out_hg = out;                                  // [G,H]
  float* out_zi = out + (size_t)N_GRAPH * H;            // [G,ZI]
  float* out_zs = out_zi + (size_t)N_GRAPH * ZIC;       // [G,ZS]
  float* out_yh = out_zs + (size_t)N_GRAPH * ZIC;       // [G]
  float* out_ev = out_yh + N_GRAPH;                     // [G,NE]

  // workspace carve-up (~118 MiB total)
  char* wp = (char*)d_ws;
  auto alloc = [&](size_t bytes) { char* p = wp; wp += (bytes + 255) & ~(size_t)255; return p; };
  bf16_t* A        = (bf16_t*)alloc((size_t)N_NODES * H * 2);   // h / t
  bf16_t* B        = (bf16_t*)alloc((size_t)N_NODES * H * 2);   // u / v
  bf16_t* Wt       = (bf16_t*)alloc((size_t)(H * ND + 6 * H * H) * 2);
  bf16_t* WtH      = (bf16_t*)alloc((size_t)(2 * ZIC * H + 4 * ZIC * ZIC) * 2);
  bf16_t* ewt16    = (bf16_t*)alloc((size_t)3 * 256 * 16 * 2);
  bf16_t* eat16    = (bf16_t*)alloc((size_t)N_EDGES * 16 * 2);
  int*    starts   = (int*)alloc((size_t)(N_GRAPH + 1) * 4);
  int*    counts   = (int*)alloc((size_t)N_NODES * 4);
  int*    cursor   = (int*)alloc((size_t)N_NODES * 4);
  int*    offs     = (int*)alloc((size_t)(N_NODES + 1) * 4);
  int*    bsum     = (int*)alloc((size_t)SCAN_B * 4);
  int*    src_srt  = (int*)alloc((size_t)N_EDGES * 4);
  bf16_t* tmp1     = (bf16_t*)alloc((size_t)N_GRAPH * ZIC * 2);
  bf16_t* tmp2     = (bf16_t*)alloc((size_t)N_GRAPH * ZIC * 2);

  const int* srcp = eidx;
  const int* dstp = eidx + N_EDGES;
  const int nscan = (N_NODES + SCAN_B - 1) / SCAN_B;

  compute_starts_kernel<<<(N_NODES + 255) / 256, 256, 0, stream>>>(
      batch, starts, counts, cursor, N_NODES, N_GRAPH);
  count_deg_kernel<<<(N_EDGES + 255) / 256, 256, 0, stream>>>(dstp, counts, N_EDGES, N_NODES);
  scan1_kernel<<<nscan, SCAN_B, 0, stream>>>(counts, offs, bsum, N_NODES);
  scan2_kernel<<<1, 64, 0, stream>>>(bsum, nscan);
  scan3_kernel<<<nscan, SCAN_B, 0, stream>>>(offs, bsum, N_NODES);
  fill_scatter_kernel<<<(N_EDGES + 255) / 256, 256, 0, stream>>>(
      srcp, dstp, eattr, offs, cursor, src_srt, eat16, N_EDGES, N_NODES);
  build_ewt16_kernel<<<(3 * 256 * 16 + 255) / 256, 256, 0, stream>>>(edge_W, ewt16);

  bf16_t* WtN = Wt;
  bf16_t* Wt1base = Wt + H * ND;                      // l-th at stride 2*H*H
  bf16_t* Wt2base = Wt + H * ND + (size_t)H * H;      // l-th at stride 2*H*H
  auto Wt1l = [&](int l) { return Wt1base + (size_t)(2 * l) * H * H; };
  auto Wt2l = [&](int l) { return Wt2base + (size_t)(2 * l) * H * H; };
  transpose_kernel<<<dim3(H / 32, ND / 32, 1), dim3(32, 8), 0, stream>>>(node_W, WtN, ND, H, 0, 0);
  transpose_kernel<<<dim3(H / 32, H / 32, 3), dim3(32, 8), 0, stream>>>(
      mlp_W1, Wt1base, H, H, (size_t)H * H, (size_t)2 * H * H);
  transpose_kernel<<<dim3(H / 32, H / 32, 3), dim3(32, 8), 0, stream>>>(
      mlp_W2, Wt2base, H, H, (size_t)H * H, (size_t)2 * H * H);

  bf16_t* fT1 = WtH;                          // [128 x 256]
  bf16_t* fT2 = fT1 + ZIC * H;                // [128 x 128]
  bf16_t* sT1 = fT2 + ZIC * ZIC;              // [128 x 256]
  bf16_t* sT2 = sT1 + ZIC * H;                // [128 x 128]
  bf16_t* pT1 = sT2 + ZIC * ZIC;              // [128 x 128]
  bf16_t* aT1 = pT1 + ZIC * ZIC;              // [128 x 128]
  transpose_kernel<<<dim3(ZIC / 32, H / 32, 1), dim3(32, 8), 0, stream>>>(finv_W1, fT1, H, ZIC, 0, 0);
  transpose_kernel<<<dim3(ZIC / 32, ZIC / 32, 1), dim3(32, 8), 0, stream>>>(finv_W2, fT2, ZIC, ZIC, 0, 0);
  transpose_kernel<<<dim3(ZIC / 32, H / 32, 1), dim3(32, 8), 0, stream>>>(fspu_W1, sT1, H, ZIC, 0, 0);
  transpose_kernel<<<dim3(ZIC / 32, ZIC / 32, 1), dim3(32, 8), 0, stream>>>(fspu_W2, sT2, ZIC, ZIC, 0, 0);
  transpose_kernel<<<dim3(ZIC / 32, ZIC / 32, 1), dim3(32, 8), 0, stream>>>(pred_W1, pT1, ZIC, ZIC, 0, 0);
  transpose_kernel<<<dim3(ZIC / 32, ZIC / 32, 1), dim3(32, 8), 0, stream>>>(adv_W1, aT1, ZIC, ZIC, 0, 0);

  dim3 ggrid((N_NODES + 127) / 128, H / 128);
  // h = x @ node_W + node_b (fp32 input -> VGPR-staging kernel)
  gemm128_kernel<ND, false, false><<<ggrid, 256, 0, stream>>>(x, WtN, node_b, A, N_NODES, H);

  const int mblocks = (N_NODES + 127) / 128;
  for (int l = 0; l < 3; ++l) {
    gine_gather_mfma_kernel<<<N_NODES / 4, 256, 0, stream>>>(
        A, eat16, src_srt, offs, ewt16 + (size_t)l * 256 * 16,
        edge_b + l * H, conv_eps + l, B);
    gemm256_dma_kernel<H, true ><<<mblocks, 512, 0, stream>>>(B, Wt1l(l), mlp_b1 + l * H, A, N_NODES);
    gemm256_dma_kernel<H, false><<<mblocks, 512, 0, stream>>>(A, Wt2l(l), mlp_b2 + l * H, B, N_NODES);
    graphnorm_kernel<<<N_GRAPH, 256, 0, stream>>>(B, A, starts, gn_w + l * H, gn_b + l * H,
                                                  gn_ms + l * H, (l == 2) ? out_hg : nullptr);
  }

  // heads via 64x64-tile GEMM, 2-way batched (fewer launches)
  dim3 hgrid2(N_GRAPH / 64, ZIC / 64, 2);
  gemm64x2_kernel<H, true, false, float><<<hgrid2, 256, 0, stream>>>(
      out_hg, fT1, finv_b1, tmp1, out_hg, sT1, fspu_b1, tmp2, N_GRAPH, ZIC);
  gemm64x2_kernel<ZIC, false, true, bf16_t><<<hgrid2, 256, 0, stream>>>(
      tmp1, fT2, finv_b2, out_zi, tmp2, sT2, fspu_b2, out_zs, N_GRAPH, ZIC);
  gemm64x2_kernel<ZIC, true, false, float><<<hgrid2, 256, 0, stream>>>(
      out_zi, pT1, pred_b1, tmp1, out_zi, aT1, adv_b1, tmp2, N_GRAPH, ZIC);
  head_out2_kernel<<<(N_GRAPH * (1 + NE) + 255) / 256, 256, 0, stream>>>(
      tmp1, pred_W2, pred_b2, out_yh, tmp2, adv_W2, adv_b2, out_ev, N_GRAPH);
}